// Round 4
// baseline (1141.405 us; speedup 1.0000x reference)
//
#include <hip/hip_runtime.h>
#include <hip/hip_bf16.h>
#include <math.h>

// ---------------------------------------------------------------------------
// EvolveGCNH + GCNConv + EdgeDecoder.
// R1: atomic scatter -> dst-CSR register gather (3574 -> 1223 us).
// R3: split-bf16 MFMA GEMMs + bf16 decode operands (1223 -> 1096 us).
// R4: (a) pure-bf16 MFMA GEMMs (storage rounding dominates anyway) -> 1/3 the
//         MFMA work, half the operand bytes, no split kernels;
//     (b) xw stored bf16 -> gather read traffic halved;
//     (c) decode via src-CSR: A[s]+b1 register-resident per wave, stream B[t].
// ---------------------------------------------------------------------------

typedef __attribute__((ext_vector_type(8))) short bf16x8;
typedef __attribute__((ext_vector_type(4))) float f32x4;

__device__ __forceinline__ unsigned f2key(float f) {
  unsigned u = __float_as_uint(f);
  return (u & 0x80000000u) ? ~u : (u | 0x80000000u);
}

// round-to-nearest-even fp32 -> bf16 bits
__device__ __forceinline__ unsigned short f2bf(float f) {
  unsigned u = __float_as_uint(f);
  unsigned r = u + 0x7fffu + ((u >> 16) & 1u);
  return (unsigned short)(r >> 16);
}
__device__ __forceinline__ float bf2f(unsigned short h) {
  return __uint_as_float((unsigned)h << 16);
}

__global__ void pnorm_kernel(const float* __restrict__ p, float* __restrict__ out) {
  int lane = threadIdx.x;  // 64 threads
  float4 v = ((const float4*)p)[lane];
  float s = v.x * v.x + v.y * v.y + v.z * v.z + v.w * v.w;
#pragma unroll
  for (int off = 32; off > 0; off >>= 1) s += __shfl_down(s, off, 64);
  if (lane == 0) out[0] = sqrtf(s);
}

__global__ __launch_bounds__(256) void score_kernel(const float* __restrict__ x,
                                                    const float* __restrict__ p,
                                                    const float* __restrict__ pn,
                                                    float* __restrict__ score, int N) {
  int node = blockIdx.x * 4 + (threadIdx.x >> 6);
  int lane = threadIdx.x & 63;
  if (node >= N) return;
  float4 xv = ((const float4*)(x + (size_t)node * 256))[lane];
  float4 pv = ((const float4*)p)[lane];
  float s = xv.x * pv.x + xv.y * pv.y + xv.z * pv.z + xv.w * pv.w;
#pragma unroll
  for (int off = 32; off > 0; off >>= 1) s += __shfl_down(s, off, 64);
  if (lane == 0) score[node] = s / pn[0];
}

// Find key of k-th largest element (4x8-bit radix passes). out[0]=threshold key.
__global__ void radix_select_kernel(const float* __restrict__ score, int n, int k,
                                    unsigned* __restrict__ out) {
  __shared__ unsigned hist[256];
  __shared__ unsigned s_prefix;
  __shared__ int s_rem;
  int tid = threadIdx.x;
  if (tid == 0) { s_prefix = 0; s_rem = k; }
  __syncthreads();
  for (int pass = 0; pass < 4; ++pass) {
    hist[tid] = 0;
    __syncthreads();
    unsigned prefix = s_prefix;
    int shift = 24 - 8 * pass;
    for (int i = tid; i < n; i += 256) {
      unsigned key = f2key(score[i]);
      bool match = (pass == 0) || ((key >> (shift + 8)) == prefix);
      if (match) atomicAdd(&hist[(key >> shift) & 255u], 1u);
    }
    __syncthreads();
    if (tid == 0) {
      int rem = s_rem;
      int c = 0;
      int b = 255;
      for (; b > 0; --b) {
        int h = (int)hist[b];
        if (c + h >= rem) break;
        c += h;
      }
      s_prefix = (prefix << 8) | (unsigned)b;
      s_rem = rem - c;
    }
    __syncthreads();
  }
  if (tid == 0) { out[0] = s_prefix; out[1] = (unsigned)s_rem; }
}

// Collect all elements with key >= T (<=1024 barring mass ties), bitonic sort
// (key desc, idx asc), emit perm[k] and tanh(score) for the top-k.
__global__ __launch_bounds__(1024) void topk_collect_sort(const float* __restrict__ score, int n, int k,
                                                          const unsigned* __restrict__ sel,
                                                          int* __restrict__ perm,
                                                          float* __restrict__ tts) {
  __shared__ unsigned keys[1024];
  __shared__ int idxs[1024];
  __shared__ int cnt;
  int tid = threadIdx.x;
  unsigned T = sel[0];
  if (tid == 0) cnt = 0;
  keys[tid] = 0u;
  idxs[tid] = 0x7fffffff;
  __syncthreads();
  for (int i = tid; i < n; i += 1024) {
    unsigned key = f2key(score[i]);
    if (key >= T) {
      int p = atomicAdd(&cnt, 1);
      if (p < 1024) { keys[p] = key; idxs[p] = i; }
    }
  }
  __syncthreads();
  for (int size = 2; size <= 1024; size <<= 1) {
    for (int stride = size >> 1; stride > 0; stride >>= 1) {
      int j = tid ^ stride;
      if (j > tid) {
        unsigned ka = keys[tid], kb = keys[j];
        int ia = idxs[tid], ib = idxs[j];
        bool aBefore = (ka > kb) || (ka == kb && ia < ib);
        bool up = ((tid & size) == 0);
        if (aBefore != up) {
          keys[tid] = kb; keys[j] = ka;
          idxs[tid] = ib; idxs[j] = ia;
        }
      }
      __syncthreads();
    }
  }
  if (tid < k) {
    int idx = idxs[tid];
    perm[tid] = idx;
    tts[tid] = tanhf(score[idx]);
  }
}

__global__ void xtilde_kernel(const float* __restrict__ x, const int* __restrict__ perm,
                              const float* __restrict__ tts, float* __restrict__ xt) {
  int b = blockIdx.x, t = threadIdx.x;
  xt[b * 256 + t] = x[(size_t)perm[b] * 256 + t] * tts[b];
}

// GRU step; writes evolved W TRANSPOSED as bf16: WevoT[n*256 + k] = bf16(W[k][n])
__global__ __launch_bounds__(256) void gru_kernel(const float* __restrict__ xt,
                                                  const float* __restrict__ Wi,
                                                  const float* __restrict__ W_ih,
                                                  const float* __restrict__ W_hh,
                                                  const float* __restrict__ b_ih,
                                                  const float* __restrict__ b_hh,
                                                  unsigned short* __restrict__ WevoT) {
  int i = blockIdx.x, j = threadIdx.x;  // i = k-row of W, j = n-col
  __shared__ float sx[256], sh[256];
  sx[j] = xt[i * 256 + j];
  sh[j] = Wi[i * 256 + j];
  __syncthreads();
  float gi[3], gh[3];
#pragma unroll
  for (int g = 0; g < 3; ++g) {
    int row = g * 256 + j;
    const float4* wi4 = (const float4*)(W_ih + (size_t)row * 256);
    const float4* wh4 = (const float4*)(W_hh + (size_t)row * 256);
    float si = 0.f, s2 = 0.f;
    for (int k4 = 0; k4 < 64; ++k4) {
      float4 wv = wi4[k4];
      float4 hv = wh4[k4];
      int k = k4 * 4;
      si += sx[k] * wv.x + sx[k + 1] * wv.y + sx[k + 2] * wv.z + sx[k + 3] * wv.w;
      s2 += sh[k] * hv.x + sh[k + 1] * hv.y + sh[k + 2] * hv.z + sh[k + 3] * hv.w;
    }
    gi[g] = si + b_ih[row];
    gh[g] = s2 + b_hh[row];
  }
  float r = 1.f / (1.f + expf(-(gi[0] + gh[0])));
  float z = 1.f / (1.f + expf(-(gi[1] + gh[1])));
  float nn = tanhf(gi[2] + r * gh[2]);
  float w = (1.f - z) * nn + z * sh[j];
  WevoT[(size_t)j * 256 + i] = f2bf(w);
}

// fp32 -> bf16 cast, float4 (4 elems) per thread
__global__ __launch_bounds__(256) void cast_bf16_kernel(const float* __restrict__ in,
                                                        unsigned short* __restrict__ outp,
                                                        int n4) {
  int i = blockIdx.x * 256 + threadIdx.x;
  if (i >= n4) return;
  float4 v = ((const float4*)in)[i];
  ushort4 hv;
  hv.x = f2bf(v.x);
  hv.y = f2bf(v.y);
  hv.z = f2bf(v.z);
  hv.w = f2bf(v.w);
  ((ushort4*)outp)[i] = hv;
}

// lin1_w [256][512] -> WA/WB bf16 each [256][256] at [n][k] (= B^T layout)
__global__ __launch_bounds__(256) void lin1_cast_kernel(const float* __restrict__ lin1,
                                                        unsigned short* __restrict__ WA,
                                                        unsigned short* __restrict__ WB) {
  int idx = blockIdx.x * 256 + threadIdx.x;  // 131072 total
  int n = idx >> 9, k = idx & 511;
  unsigned short h = f2bf(lin1[idx]);
  if (k < 256)
    WA[n * 256 + k] = h;
  else
    WB[n * 256 + (k - 256)] = h;
}

// ---------------------------------------------------------------------------
// Pure-bf16 MFMA GEMM: C[M,256] = A[M,256] @ B[256,256], bf16 in, bf16 out,
// fp32 accumulate. A row-major bf16; B as B^T rows (BT[n][k]).
// Block: 256 thr = 4 waves; tile 64(M) x 256(N); wave w -> cols [64w, 64w+64).
// mfma_f32_16x16x32_bf16 layouts (HW-verified, R3-validated):
//   A-frag: A[m = lane&15][k = (lane>>4)*8 + j]
//   B-frag: B[k = (lane>>4)*8 + j][n = lane&15]  -> read BT[n][k] rows
//   C/D   : col = lane&15, row = (lane>>4)*4 + reg
// ---------------------------------------------------------------------------
__global__ __launch_bounds__(256) void mfma_gemm_bf16(const unsigned short* __restrict__ A,
                                                      const unsigned short* __restrict__ BT,
                                                      unsigned short* __restrict__ Cout, int M) {
  int tid = threadIdx.x;
  int wave = tid >> 6, lane = tid & 63;
  int quad = lane >> 4, r16 = lane & 15;
  int n0 = wave * 64;
  int mbase = blockIdx.x * 64;

  f32x4 acc[4][4];
#pragma unroll
  for (int i = 0; i < 4; ++i)
#pragma unroll
    for (int j = 0; j < 4; ++j) acc[i][j] = (f32x4){0.f, 0.f, 0.f, 0.f};

  for (int k0 = 0; k0 < 256; k0 += 32) {
    int koff = k0 + quad * 8;
    bf16x8 af[4], bf[4];
#pragma unroll
    for (int mt = 0; mt < 4; ++mt) {
      int row = mbase + mt * 16 + r16;
      row = row < M ? row : M - 1;
      af[mt] = *(const bf16x8*)(A + (size_t)row * 256 + koff);
    }
#pragma unroll
    for (int nt = 0; nt < 4; ++nt) {
      int nrow = n0 + nt * 16 + r16;
      bf[nt] = *(const bf16x8*)(BT + (size_t)nrow * 256 + koff);
    }
#pragma unroll
    for (int mt = 0; mt < 4; ++mt)
#pragma unroll
      for (int nt = 0; nt < 4; ++nt)
        acc[mt][nt] = __builtin_amdgcn_mfma_f32_16x16x32_bf16(af[mt], bf[nt], acc[mt][nt], 0, 0, 0);
  }
#pragma unroll
  for (int mt = 0; mt < 4; ++mt) {
#pragma unroll
    for (int rr = 0; rr < 4; ++rr) {
      int grow = mbase + mt * 16 + quad * 4 + rr;
      if (grow < M) {
#pragma unroll
        for (int nt = 0; nt < 4; ++nt)
          Cout[(size_t)grow * 256 + n0 + nt * 16 + r16] = f2bf(acc[mt][nt][rr]);
      }
    }
  }
}

__global__ void zero_kernel(float4* __restrict__ p, int n4) {
  int i = blockIdx.x * blockDim.x + threadIdx.x;
  if (i < n4) p[i] = make_float4(0.f, 0.f, 0.f, 0.f);
}

// counts[dst]++ and deg[dst] += attr, one pass over conv edges
__global__ void hist_deg_kernel(const int* __restrict__ ei, const float* __restrict__ attr,
                                int* __restrict__ cnt, float* __restrict__ deg, int E) {
  int e = blockIdx.x * blockDim.x + threadIdx.x;
  if (e < E) {
    int d = ei[E + e];
    atomicAdd(&cnt[d], 1);
    atomicAdd(&deg[d], attr[e]);
  }
}

// counts[src]++ over decoder edges
__global__ void hist_src_kernel(const int* __restrict__ ewi, int* __restrict__ cnt, int E) {
  int e = blockIdx.x * blockDim.x + threadIdx.x;
  if (e < E) atomicAdd(&cnt[ewi[e]], 1);
}

__global__ void dinv_kernel(const float* __restrict__ deg, float* __restrict__ dinv, int n) {
  int i = blockIdx.x * blockDim.x + threadIdx.x;
  if (i < n) {
    float d = deg[i];
    dinv[i] = d > 0.f ? 1.f / sqrtf(d) : 0.f;
  }
}

// exclusive prefix sum of cnt[0..N) -> row_ptr[0..N], plus a cursor copy
__global__ __launch_bounds__(1024) void scan_kernel(const int* __restrict__ cnt,
                                                    int* __restrict__ row_ptr,
                                                    int* __restrict__ cursor, int N) {
  __shared__ int ssum[1024];
  int tid = threadIdx.x;
  int chunk = (N + 1023) / 1024;
  int beg = tid * chunk;
  int end = beg + chunk < N ? beg + chunk : N;
  int s = 0;
  for (int i = beg; i < end; ++i) s += cnt[i];
  ssum[tid] = s;
  __syncthreads();
  for (int off = 1; off < 1024; off <<= 1) {
    int v = ssum[tid];
    int add = (tid >= off) ? ssum[tid - off] : 0;
    __syncthreads();
    ssum[tid] = v + add;
    __syncthreads();
  }
  int run = (tid == 0) ? 0 : ssum[tid - 1];
  for (int i = beg; i < end; ++i) {
    row_ptr[i] = run;
    cursor[i] = run;
    run += cnt[i];
  }
  if (tid == 1023) row_ptr[N] = run;
}

// conv CSR fill: es[pos] = src, ev[pos] = dinv[src]*attr
__global__ void csr_fill_kernel(const int* __restrict__ ei, const float* __restrict__ attr,
                                const float* __restrict__ dinv, int* __restrict__ cursor,
                                int* __restrict__ es, float* __restrict__ ev, int E) {
  int e = blockIdx.x * blockDim.x + threadIdx.x;
  if (e < E) {
    int s = ei[e], d = ei[E + e];
    int pos = atomicAdd(&cursor[d], 1);
    es[pos] = s;
    ev[pos] = dinv[s] * attr[e];
  }
}

// decoder CSR fill (grouped by src): et[pos] = dst, eo[pos] = original edge id
__global__ void csr_fill_src_kernel(const int* __restrict__ ewi, int* __restrict__ cursor,
                                    int* __restrict__ et, int* __restrict__ eo, int E) {
  int e = blockIdx.x * blockDim.x + threadIdx.x;
  if (e < E) {
    int s = ewi[e];
    int pos = atomicAdd(&cursor[s], 1);
    et[pos] = ewi[E + e];
    eo[pos] = e;
  }
}

// one wave per dst node: fp32 accumulate bf16 xw rows; write ne bf16
__global__ __launch_bounds__(256) void gcn_gather(const unsigned short* __restrict__ xw,
                                                  const int* __restrict__ row_ptr,
                                                  const int* __restrict__ es,
                                                  const float* __restrict__ ev,
                                                  const float* __restrict__ dinv,
                                                  unsigned short* __restrict__ ne, int N) {
  int node = blockIdx.x * 4 + (threadIdx.x >> 6);
  int lane = threadIdx.x & 63;
  if (node >= N) return;
  int beg = row_ptr[node], end = row_ptr[node + 1];
  float ax = 0.f, ay = 0.f, az = 0.f, aw = 0.f;
  int j = beg;
  if (j < end) {
    int s = es[j];
    float v = ev[j];
    for (; j < end;) {
      int ns = 0; float nv = 0.f;
      if (j + 1 < end) { ns = es[j + 1]; nv = ev[j + 1]; }
      ushort4 xv = ((const ushort4*)(xw + (size_t)s * 256))[lane];
      ax += bf2f(xv.x) * v;
      ay += bf2f(xv.y) * v;
      az += bf2f(xv.z) * v;
      aw += bf2f(xv.w) * v;
      s = ns; v = nv;
      ++j;
    }
  }
  float dd = dinv[node];
  ushort4 hv;
  hv.x = f2bf(ax * dd);
  hv.y = f2bf(ay * dd);
  hv.z = f2bf(az * dd);
  hv.w = f2bf(aw * dd);
  ((ushort4*)(ne + (size_t)node * 256))[lane] = hv;
}

// decode grouped by src: one wave per src node; A[s]+b1 stays in registers,
// stream B[t] per edge; scatter pred to original edge order.
__global__ __launch_bounds__(256) void edge_decode_csr(const unsigned short* __restrict__ A,
                                                       const unsigned short* __restrict__ Bm,
                                                       const int* __restrict__ row_ptr,
                                                       const int* __restrict__ et,
                                                       const int* __restrict__ eo,
                                                       const float* __restrict__ b1,
                                                       const float* __restrict__ w2,
                                                       const float* __restrict__ b2,
                                                       float* __restrict__ out, int N) {
  int node = blockIdx.x * 4 + (threadIdx.x >> 6);
  int lane = threadIdx.x & 63;
  if (node >= N) return;
  int beg = row_ptr[node], end = row_ptr[node + 1];
  if (beg >= end) return;
  ushort4 a4 = ((const ushort4*)(A + (size_t)node * 256))[lane];
  float4 bb = ((const float4*)b1)[lane];
  float4 w = ((const float4*)w2)[lane];
  float a0 = bf2f(a4.x) + bb.x;
  float a1 = bf2f(a4.y) + bb.y;
  float a2 = bf2f(a4.z) + bb.z;
  float a3 = bf2f(a4.w) + bb.w;
  float base = b2[0];
  int t = et[beg];
  for (int j = beg; j < end; ++j) {
    int tn = (j + 1 < end) ? et[j + 1] : 0;
    int oe = eo[j];
    ushort4 b4 = ((const ushort4*)(Bm + (size_t)t * 256))[lane];
    float h0 = fmaxf(a0 + bf2f(b4.x), 0.f);
    float h1 = fmaxf(a1 + bf2f(b4.y), 0.f);
    float h2 = fmaxf(a2 + bf2f(b4.z), 0.f);
    float h3 = fmaxf(a3 + bf2f(b4.w), 0.f);
    float p = h0 * w.x + h1 * w.y + h2 * w.z + h3 * w.w;
#pragma unroll
    for (int off = 32; off > 0; off >>= 1) p += __shfl_down(p, off, 64);
    if (lane == 0) out[oe] = p + base;
    t = tn;
  }
}

extern "C" void kernel_launch(void* const* d_in, const int* in_sizes, int n_in,
                              void* d_out, int out_size, void* d_ws, size_t ws_size,
                              hipStream_t stream) {
  const float* x      = (const float*)d_in[0];
  const int*   ei     = (const int*)d_in[1];
  const float* attr   = (const float*)d_in[2];
  const int*   ewi    = (const int*)d_in[3];
  const float* p_pool = (const float*)d_in[4];
  const float* W_ih   = (const float*)d_in[5];
  const float* W_hh   = (const float*)d_in[6];
  const float* b_ih   = (const float*)d_in[7];
  const float* b_hh   = (const float*)d_in[8];
  const float* W_init = (const float*)d_in[9];
  const float* lin1_w = (const float*)d_in[10];
  const float* lin1_b = (const float*)d_in[11];
  const float* lin2_w = (const float*)d_in[12];
  const float* lin2_b = (const float*)d_in[13];
  float* out = (float*)d_out;

  const int C = 256;
  const int N = in_sizes[0] / C;   // 50000
  const int E = in_sizes[2];       // 800000

  // ---- workspace layout (256B aligned) ----
  char* ws = (char*)d_ws;
  size_t off = 0;
  auto alloc = [&](size_t bytes) {
    size_t o = off;
    off = (off + bytes + 255) & ~(size_t)255;
    return o;
  };
  float*          score   = (float*)(ws + alloc((size_t)N * 4));
  float*          pnorm   = (float*)(ws + alloc(4));
  unsigned*       sel     = (unsigned*)(ws + alloc(8));
  int*            perm    = (int*)(ws + alloc(C * 4));
  float*          tts     = (float*)(ws + alloc(C * 4));
  float*          xt      = (float*)(ws + alloc((size_t)C * C * 4));
  unsigned short* WevoT   = (unsigned short*)(ws + alloc((size_t)C * C * 2));
  unsigned short* WA      = (unsigned short*)(ws + alloc((size_t)C * C * 2));
  unsigned short* WB      = (unsigned short*)(ws + alloc((size_t)C * C * 2));
  float*          deg     = (float*)(ws + alloc((size_t)N * 4));
  float*          dinv    = (float*)(ws + alloc((size_t)N * 4));
  int*            cnt     = (int*)(ws + alloc((size_t)N * 4));
  int*            rowp    = (int*)(ws + alloc((size_t)(N + 1) * 4));
  int*            cursor  = (int*)(ws + alloc((size_t)N * 4));
  int*            cnt2    = (int*)(ws + alloc((size_t)N * 4));
  int*            rowp2   = (int*)(ws + alloc((size_t)(N + 1) * 4));
  int*            cursor2 = (int*)(ws + alloc((size_t)N * 4));
  int*            es      = (int*)(ws + alloc((size_t)E * 4));
  float*          ev      = (float*)(ws + alloc((size_t)E * 4));
  int*            et      = (int*)(ws + alloc((size_t)E * 4));
  int*            eo      = (int*)(ws + alloc((size_t)E * 4));
  unsigned short* xh      = (unsigned short*)(ws + alloc((size_t)N * C * 2));
  unsigned short* xwh     = (unsigned short*)(ws + alloc((size_t)N * C * 2));
  unsigned short* Bbf     = (unsigned short*)(ws + alloc((size_t)N * C * 2));
  // aliases (stream-ordered producers/consumers):
  unsigned short* ne  = xh;   // xh dead after GEMM1
  unsigned short* Abf = xwh;  // xwh dead after gather

  // 1) score
  pnorm_kernel<<<1, 64, 0, stream>>>(p_pool, pnorm);
  score_kernel<<<(N + 3) / 4, 256, 0, stream>>>(x, p_pool, pnorm, score, N);

  // 2) exact top-256 (sorted desc, ties -> lower index)
  radix_select_kernel<<<1, 256, 0, stream>>>(score, N, C, sel);
  topk_collect_sort<<<1, 1024, 0, stream>>>(score, N, C, sel, perm, tts);

  // 3) x_tilde
  xtilde_kernel<<<C, C, 0, stream>>>(x, perm, tts, xt);

  // 4) GRU -> evolved W (transposed bf16)
  gru_kernel<<<C, C, 0, stream>>>(xt, W_init, W_ih, W_hh, b_ih, b_hh, WevoT);

  // 5) xw = x @ Wevo (bf16 MFMA, bf16 out)
  cast_bf16_kernel<<<(N * C / 4 + 255) / 256, 256, 0, stream>>>(x, xh, N * C / 4);
  mfma_gemm_bf16<<<(N + 63) / 64, 256, 0, stream>>>(xh, WevoT, xwh, N);

  // 6) GCN: dst-CSR build + register gather (also build decoder src-CSR here)
  zero_kernel<<<(N / 4 + 255) / 256, 256, 0, stream>>>((float4*)deg, N / 4);
  zero_kernel<<<(N / 4 + 255) / 256, 256, 0, stream>>>((float4*)cnt, N / 4);
  zero_kernel<<<(N / 4 + 255) / 256, 256, 0, stream>>>((float4*)cnt2, N / 4);
  hist_deg_kernel<<<(E + 255) / 256, 256, 0, stream>>>(ei, attr, cnt, deg, E);
  hist_src_kernel<<<(E + 255) / 256, 256, 0, stream>>>(ewi, cnt2, E);
  dinv_kernel<<<(N + 255) / 256, 256, 0, stream>>>(deg, dinv, N);
  scan_kernel<<<1, 1024, 0, stream>>>(cnt, rowp, cursor, N);
  scan_kernel<<<1, 1024, 0, stream>>>(cnt2, rowp2, cursor2, N);
  csr_fill_kernel<<<(E + 255) / 256, 256, 0, stream>>>(ei, attr, dinv, cursor, es, ev, E);
  csr_fill_src_kernel<<<(E + 255) / 256, 256, 0, stream>>>(ewi, cursor2, et, eo, E);
  gcn_gather<<<(N + 3) / 4, 256, 0, stream>>>(xwh, rowp, es, ev, dinv, ne, N);

  // 7) decoder projections (lin1_w rows ARE the B^T layout)
  lin1_cast_kernel<<<(2 * C * C) / 256, 256, 0, stream>>>(lin1_w, WA, WB);
  mfma_gemm_bf16<<<(N + 63) / 64, 256, 0, stream>>>(ne, WA, Abf, N);
  mfma_gemm_bf16<<<(N + 63) / 64, 256, 0, stream>>>(ne, WB, Bbf, N);

  // 8) edge decode grouped by src (A-row register-resident)
  edge_decode_csr<<<(N + 3) / 4, 256, 0, stream>>>(Abf, Bbf, rowp2, et, eo,
                                                   lin1_b, lin2_w, lin2_b, out, N);
}

// Round 5
// 962.044 us; speedup vs baseline: 1.1864x; 1.1864x over previous
//
#include <hip/hip_runtime.h>
#include <hip/hip_bf16.h>
#include <math.h>

// ---------------------------------------------------------------------------
// EvolveGCNH + GCNConv + EdgeDecoder.
// R1: atomic scatter -> dst-CSR register gather (3574 -> 1223 us).
// R3: split-bf16 MFMA GEMMs + bf16 decode operands (1223 -> 1096 us).
// R4: pure-bf16 GEMMs, bf16 xw, src-CSR grouped decode (1141 us; exposed
//     radix_select_kernel = 163 us single-block latency bomb).
// R5: (a) top-k via grid-wide 12-bit histogram + parallel suffix-select
//         (bin-floor threshold; collect+sort unchanged);
//     (b) merged edge-histogram pass and merged CSR-fill pass, int2-packed
//         CSR payloads (1 load/edge);
//     (c) fused dual decoder GEMM (reads ne once);
//     (d) double-buffered row loads in gather and decode.
// ---------------------------------------------------------------------------

typedef __attribute__((ext_vector_type(8))) short bf16x8;
typedef __attribute__((ext_vector_type(4))) float f32x4;

__device__ __forceinline__ unsigned f2key(float f) {
  unsigned u = __float_as_uint(f);
  return (u & 0x80000000u) ? ~u : (u | 0x80000000u);
}

// round-to-nearest-even fp32 -> bf16 bits
__device__ __forceinline__ unsigned short f2bf(float f) {
  unsigned u = __float_as_uint(f);
  unsigned r = u + 0x7fffu + ((u >> 16) & 1u);
  return (unsigned short)(r >> 16);
}
__device__ __forceinline__ float bf2f(unsigned short h) {
  return __uint_as_float((unsigned)h << 16);
}

__global__ void pnorm_kernel(const float* __restrict__ p, float* __restrict__ out) {
  int lane = threadIdx.x;  // 64 threads
  float4 v = ((const float4*)p)[lane];
  float s = v.x * v.x + v.y * v.y + v.z * v.z + v.w * v.w;
#pragma unroll
  for (int off = 32; off > 0; off >>= 1) s += __shfl_down(s, off, 64);
  if (lane == 0) out[0] = sqrtf(s);
}

__global__ __launch_bounds__(256) void score_kernel(const float* __restrict__ x,
                                                    const float* __restrict__ p,
                                                    const float* __restrict__ pn,
                                                    float* __restrict__ score, int N) {
  int node = blockIdx.x * 4 + (threadIdx.x >> 6);
  int lane = threadIdx.x & 63;
  if (node >= N) return;
  float4 xv = ((const float4*)(x + (size_t)node * 256))[lane];
  float4 pv = ((const float4*)p)[lane];
  float s = xv.x * pv.x + xv.y * pv.y + xv.z * pv.z + xv.w * pv.w;
#pragma unroll
  for (int off = 32; off > 0; off >>= 1) s += __shfl_down(s, off, 64);
  if (lane == 0) score[node] = s / pn[0];
}

// grid-wide histogram of the top 12 key bits (4096 bins)
__global__ __launch_bounds__(256) void hist12_kernel(const float* __restrict__ score, int n,
                                                     int* __restrict__ gh) {
  __shared__ int lh[4096];
  int tid = threadIdx.x;
  for (int i = tid; i < 4096; i += 256) lh[i] = 0;
  __syncthreads();
  int idx = blockIdx.x * 256 + tid;
  int stride = gridDim.x * 256;
  for (int i = idx; i < n; i += stride) {
    unsigned key = f2key(score[i]);
    atomicAdd(&lh[key >> 20], 1);
  }
  __syncthreads();
  for (int i = tid; i < 4096; i += 256) {
    int v = lh[i];
    if (v) atomicAdd(&gh[i], v);
  }
}

// find highest bin b with suffix-count(b) >= k; sel[0] = bin floor key
__global__ __launch_bounds__(1024) void select12_kernel(const int* __restrict__ gh, int k,
                                                        unsigned* __restrict__ sel) {
  __shared__ int part[1024];
  int tid = threadIdx.x;
  int b0 = tid * 4;
  int s0 = gh[b0], s1 = gh[b0 + 1], s2 = gh[b0 + 2], s3 = gh[b0 + 3];
  part[tid] = s0 + s1 + s2 + s3;
  __syncthreads();
  for (int off = 1; off < 1024; off <<= 1) {
    int v = part[tid];
    int add = (tid + off < 1024) ? part[tid + off] : 0;
    __syncthreads();
    part[tid] = v + add;
    __syncthreads();
  }
  int sufChunk = part[tid];
  int sufNext = (tid < 1023) ? part[tid + 1] : 0;
  if (sufNext < k && sufChunk >= k) {
    int run = sufNext;
    int b;
    run += s3;
    if (run >= k) b = b0 + 3;
    else {
      run += s2;
      if (run >= k) b = b0 + 2;
      else {
        run += s1;
        b = (run >= k) ? b0 + 1 : b0;
      }
    }
    sel[0] = ((unsigned)b) << 20;
  }
}

// Collect all elements with key >= T (bin floor; <=~450 for this data), bitonic
// sort (key desc, idx asc), emit perm[k] and tanh(score) for the top-k.
__global__ __launch_bounds__(1024) void topk_collect_sort(const float* __restrict__ score, int n, int k,
                                                          const unsigned* __restrict__ sel,
                                                          int* __restrict__ perm,
                                                          float* __restrict__ tts) {
  __shared__ unsigned keys[1024];
  __shared__ int idxs[1024];
  __shared__ int cnt;
  int tid = threadIdx.x;
  unsigned T = sel[0];
  if (tid == 0) cnt = 0;
  keys[tid] = 0u;
  idxs[tid] = 0x7fffffff;
  __syncthreads();
  for (int i = tid; i < n; i += 1024) {
    unsigned key = f2key(score[i]);
    if (key >= T) {
      int p = atomicAdd(&cnt, 1);
      if (p < 1024) { keys[p] = key; idxs[p] = i; }
    }
  }
  __syncthreads();
  for (int size = 2; size <= 1024; size <<= 1) {
    for (int stride = size >> 1; stride > 0; stride >>= 1) {
      int j = tid ^ stride;
      if (j > tid) {
        unsigned ka = keys[tid], kb = keys[j];
        int ia = idxs[tid], ib = idxs[j];
        bool aBefore = (ka > kb) || (ka == kb && ia < ib);
        bool up = ((tid & size) == 0);
        if (aBefore != up) {
          keys[tid] = kb; keys[j] = ka;
          idxs[tid] = ib; idxs[j] = ia;
        }
      }
      __syncthreads();
    }
  }
  if (tid < k) {
    int idx = idxs[tid];
    perm[tid] = idx;
    tts[tid] = tanhf(score[idx]);
  }
}

__global__ void xtilde_kernel(const float* __restrict__ x, const int* __restrict__ perm,
                              const float* __restrict__ tts, float* __restrict__ xt) {
  int b = blockIdx.x, t = threadIdx.x;
  xt[b * 256 + t] = x[(size_t)perm[b] * 256 + t] * tts[b];
}

// GRU step; writes evolved W TRANSPOSED as bf16: WevoT[n*256 + k] = bf16(W[k][n])
__global__ __launch_bounds__(256) void gru_kernel(const float* __restrict__ xt,
                                                  const float* __restrict__ Wi,
                                                  const float* __restrict__ W_ih,
                                                  const float* __restrict__ W_hh,
                                                  const float* __restrict__ b_ih,
                                                  const float* __restrict__ b_hh,
                                                  unsigned short* __restrict__ WevoT) {
  int i = blockIdx.x, j = threadIdx.x;  // i = k-row of W, j = n-col
  __shared__ float sx[256], sh[256];
  sx[j] = xt[i * 256 + j];
  sh[j] = Wi[i * 256 + j];
  __syncthreads();
  float gi[3], gh[3];
#pragma unroll
  for (int g = 0; g < 3; ++g) {
    int row = g * 256 + j;
    const float4* wi4 = (const float4*)(W_ih + (size_t)row * 256);
    const float4* wh4 = (const float4*)(W_hh + (size_t)row * 256);
    float si = 0.f, s2 = 0.f;
    for (int k4 = 0; k4 < 64; ++k4) {
      float4 wv = wi4[k4];
      float4 hv = wh4[k4];
      int k = k4 * 4;
      si += sx[k] * wv.x + sx[k + 1] * wv.y + sx[k + 2] * wv.z + sx[k + 3] * wv.w;
      s2 += sh[k] * hv.x + sh[k + 1] * hv.y + sh[k + 2] * hv.z + sh[k + 3] * hv.w;
    }
    gi[g] = si + b_ih[row];
    gh[g] = s2 + b_hh[row];
  }
  float r = 1.f / (1.f + expf(-(gi[0] + gh[0])));
  float z = 1.f / (1.f + expf(-(gi[1] + gh[1])));
  float nn = tanhf(gi[2] + r * gh[2]);
  float w = (1.f - z) * nn + z * sh[j];
  WevoT[(size_t)j * 256 + i] = f2bf(w);
}

// fp32 -> bf16 cast, float4 (4 elems) per thread
__global__ __launch_bounds__(256) void cast_bf16_kernel(const float* __restrict__ in,
                                                        unsigned short* __restrict__ outp,
                                                        int n4) {
  int i = blockIdx.x * 256 + threadIdx.x;
  if (i >= n4) return;
  float4 v = ((const float4*)in)[i];
  ushort4 hv;
  hv.x = f2bf(v.x);
  hv.y = f2bf(v.y);
  hv.z = f2bf(v.z);
  hv.w = f2bf(v.w);
  ((ushort4*)outp)[i] = hv;
}

// lin1_w [256][512] -> WA/WB bf16 each [256][256] at [n][k] (= B^T layout)
__global__ __launch_bounds__(256) void lin1_cast_kernel(const float* __restrict__ lin1,
                                                        unsigned short* __restrict__ WA,
                                                        unsigned short* __restrict__ WB) {
  int idx = blockIdx.x * 256 + threadIdx.x;  // 131072 total
  int n = idx >> 9, k = idx & 511;
  unsigned short h = f2bf(lin1[idx]);
  if (k < 256)
    WA[n * 256 + k] = h;
  else
    WB[n * 256 + (k - 256)] = h;
}

// ---------------------------------------------------------------------------
// Pure-bf16 MFMA GEMM: C[M,256] = A[M,256] @ B[256,256], bf16 in/out, fp32 acc.
// A row-major bf16; B as B^T rows (BT[n][k]). Layouts HW-verified (R3/R4).
// ---------------------------------------------------------------------------
__global__ __launch_bounds__(256) void mfma_gemm_bf16(const unsigned short* __restrict__ A,
                                                      const unsigned short* __restrict__ BT,
                                                      unsigned short* __restrict__ Cout, int M) {
  int tid = threadIdx.x;
  int wave = tid >> 6, lane = tid & 63;
  int quad = lane >> 4, r16 = lane & 15;
  int n0 = wave * 64;
  int mbase = blockIdx.x * 64;

  f32x4 acc[4][4];
#pragma unroll
  for (int i = 0; i < 4; ++i)
#pragma unroll
    for (int j = 0; j < 4; ++j) acc[i][j] = (f32x4){0.f, 0.f, 0.f, 0.f};

  for (int k0 = 0; k0 < 256; k0 += 32) {
    int koff = k0 + quad * 8;
    bf16x8 af[4], bf[4];
#pragma unroll
    for (int mt = 0; mt < 4; ++mt) {
      int row = mbase + mt * 16 + r16;
      row = row < M ? row : M - 1;
      af[mt] = *(const bf16x8*)(A + (size_t)row * 256 + koff);
    }
#pragma unroll
    for (int nt = 0; nt < 4; ++nt) {
      int nrow = n0 + nt * 16 + r16;
      bf[nt] = *(const bf16x8*)(BT + (size_t)nrow * 256 + koff);
    }
#pragma unroll
    for (int mt = 0; mt < 4; ++mt)
#pragma unroll
      for (int nt = 0; nt < 4; ++nt)
        acc[mt][nt] = __builtin_amdgcn_mfma_f32_16x16x32_bf16(af[mt], bf[nt], acc[mt][nt], 0, 0, 0);
  }
#pragma unroll
  for (int mt = 0; mt < 4; ++mt) {
#pragma unroll
    for (int rr = 0; rr < 4; ++rr) {
      int grow = mbase + mt * 16 + quad * 4 + rr;
      if (grow < M) {
#pragma unroll
        for (int nt = 0; nt < 4; ++nt)
          Cout[(size_t)grow * 256 + n0 + nt * 16 + r16] = f2bf(acc[mt][nt][rr]);
      }
    }
  }
}

// Dual variant: reads A once, produces C1 = A@B1 and C2 = A@B2.
__global__ __launch_bounds__(256) void mfma_gemm_bf16_dual(const unsigned short* __restrict__ A,
                                                           const unsigned short* __restrict__ BT1,
                                                           const unsigned short* __restrict__ BT2,
                                                           unsigned short* __restrict__ C1,
                                                           unsigned short* __restrict__ C2, int M) {
  int tid = threadIdx.x;
  int wave = tid >> 6, lane = tid & 63;
  int quad = lane >> 4, r16 = lane & 15;
  int n0 = wave * 64;
  int mbase = blockIdx.x * 64;

  f32x4 acc1[4][4], acc2[4][4];
#pragma unroll
  for (int i = 0; i < 4; ++i)
#pragma unroll
    for (int j = 0; j < 4; ++j) {
      acc1[i][j] = (f32x4){0.f, 0.f, 0.f, 0.f};
      acc2[i][j] = (f32x4){0.f, 0.f, 0.f, 0.f};
    }

  for (int k0 = 0; k0 < 256; k0 += 32) {
    int koff = k0 + quad * 8;
    bf16x8 af[4], b1[4], b2[4];
#pragma unroll
    for (int mt = 0; mt < 4; ++mt) {
      int row = mbase + mt * 16 + r16;
      row = row < M ? row : M - 1;
      af[mt] = *(const bf16x8*)(A + (size_t)row * 256 + koff);
    }
#pragma unroll
    for (int nt = 0; nt < 4; ++nt) {
      int nrow = n0 + nt * 16 + r16;
      b1[nt] = *(const bf16x8*)(BT1 + (size_t)nrow * 256 + koff);
      b2[nt] = *(const bf16x8*)(BT2 + (size_t)nrow * 256 + koff);
    }
#pragma unroll
    for (int mt = 0; mt < 4; ++mt)
#pragma unroll
      for (int nt = 0; nt < 4; ++nt) {
        acc1[mt][nt] = __builtin_amdgcn_mfma_f32_16x16x32_bf16(af[mt], b1[nt], acc1[mt][nt], 0, 0, 0);
        acc2[mt][nt] = __builtin_amdgcn_mfma_f32_16x16x32_bf16(af[mt], b2[nt], acc2[mt][nt], 0, 0, 0);
      }
  }
#pragma unroll
  for (int mt = 0; mt < 4; ++mt) {
#pragma unroll
    for (int rr = 0; rr < 4; ++rr) {
      int grow = mbase + mt * 16 + quad * 4 + rr;
      if (grow < M) {
#pragma unroll
        for (int nt = 0; nt < 4; ++nt) {
          size_t o = (size_t)grow * 256 + n0 + nt * 16 + r16;
          C1[o] = f2bf(acc1[mt][nt][rr]);
          C2[o] = f2bf(acc2[mt][nt][rr]);
        }
      }
    }
  }
}

__global__ void zero_kernel(float4* __restrict__ p, int n4) {
  int i = blockIdx.x * blockDim.x + threadIdx.x;
  if (i < n4) p[i] = make_float4(0.f, 0.f, 0.f, 0.f);
}

// one pass over all edges: conv-dst count+deg, decoder-src count
__global__ void build_hist_kernel(const int* __restrict__ ei, const float* __restrict__ attr,
                                  const int* __restrict__ ewi,
                                  int* __restrict__ cnt, float* __restrict__ deg,
                                  int* __restrict__ cnt2, int E) {
  int e = blockIdx.x * blockDim.x + threadIdx.x;
  if (e < E) {
    int d = ei[E + e];
    atomicAdd(&cnt[d], 1);
    atomicAdd(&deg[d], attr[e]);
    atomicAdd(&cnt2[ewi[e]], 1);
  }
}

__global__ void dinv_kernel(const float* __restrict__ deg, float* __restrict__ dinv, int n) {
  int i = blockIdx.x * blockDim.x + threadIdx.x;
  if (i < n) {
    float d = deg[i];
    dinv[i] = d > 0.f ? 1.f / sqrtf(d) : 0.f;
  }
}

// exclusive prefix sum of cnt[0..N) -> row_ptr[0..N], plus a cursor copy
__global__ __launch_bounds__(1024) void scan_kernel(const int* __restrict__ cnt,
                                                    int* __restrict__ row_ptr,
                                                    int* __restrict__ cursor, int N) {
  __shared__ int ssum[1024];
  int tid = threadIdx.x;
  int chunk = (N + 1023) / 1024;
  int beg = tid * chunk;
  int end = beg + chunk < N ? beg + chunk : N;
  int s = 0;
  for (int i = beg; i < end; ++i) s += cnt[i];
  ssum[tid] = s;
  __syncthreads();
  for (int off = 1; off < 1024; off <<= 1) {
    int v = ssum[tid];
    int add = (tid >= off) ? ssum[tid - off] : 0;
    __syncthreads();
    ssum[tid] = v + add;
    __syncthreads();
  }
  int run = (tid == 0) ? 0 : ssum[tid - 1];
  for (int i = beg; i < end; ++i) {
    row_ptr[i] = run;
    cursor[i] = run;
    run += cnt[i];
  }
  if (tid == 1023) row_ptr[N] = run;
}

// one pass over all edges: fill both CSRs with packed int2 payloads.
// esv[pos] = (src, bits(dinv[src]*attr));  eto[pos2] = (dst, edge_id)
__global__ void csr_fill_merged(const int* __restrict__ ei, const float* __restrict__ attr,
                                const float* __restrict__ dinv, const int* __restrict__ ewi,
                                int* __restrict__ cursor, int* __restrict__ cursor2,
                                int2* __restrict__ esv, int2* __restrict__ eto, int E) {
  int e = blockIdx.x * blockDim.x + threadIdx.x;
  if (e < E) {
    int s = ei[e], d = ei[E + e];
    int pos = atomicAdd(&cursor[d], 1);
    esv[pos] = make_int2(s, __float_as_int(dinv[s] * attr[e]));
    int s2 = ewi[e];
    int pos2 = atomicAdd(&cursor2[s2], 1);
    eto[pos2] = make_int2(ewi[E + e], e);
  }
}

// one wave per dst node: fp32 accumulate bf16 xw rows; double-buffered loads
__global__ __launch_bounds__(256) void gcn_gather(const unsigned short* __restrict__ xw,
                                                  const int* __restrict__ row_ptr,
                                                  const int2* __restrict__ esv,
                                                  const float* __restrict__ dinv,
                                                  unsigned short* __restrict__ ne, int N) {
  int node = blockIdx.x * 4 + (threadIdx.x >> 6);
  int lane = threadIdx.x & 63;
  if (node >= N) return;
  int beg = row_ptr[node], end = row_ptr[node + 1];
  float ax = 0.f, ay = 0.f, az = 0.f, aw = 0.f;
  if (beg < end) {
    int2 e0 = esv[beg];
    ushort4 x0 = ((const ushort4*)(xw + (size_t)e0.x * 256))[lane];
    for (int j = beg + 1; j <= end; ++j) {
      int2 e1 = e0;
      ushort4 x1 = x0;
      if (j < end) {
        e1 = esv[j];
        x1 = ((const ushort4*)(xw + (size_t)e1.x * 256))[lane];
      }
      float v = __int_as_float(e0.y);
      ax += bf2f(x0.x) * v;
      ay += bf2f(x0.y) * v;
      az += bf2f(x0.z) * v;
      aw += bf2f(x0.w) * v;
      e0 = e1;
      x0 = x1;
    }
  }
  float dd = dinv[node];
  ushort4 hv;
  hv.x = f2bf(ax * dd);
  hv.y = f2bf(ay * dd);
  hv.z = f2bf(az * dd);
  hv.w = f2bf(aw * dd);
  ((ushort4*)(ne + (size_t)node * 256))[lane] = hv;
}

// decode grouped by src: one wave per src node; A[s]+b1 register-resident,
// stream B[t] double-buffered; scatter pred to original edge order.
__global__ __launch_bounds__(256) void edge_decode_csr(const unsigned short* __restrict__ A,
                                                       const unsigned short* __restrict__ Bm,
                                                       const int* __restrict__ row_ptr,
                                                       const int2* __restrict__ eto,
                                                       const float* __restrict__ b1,
                                                       const float* __restrict__ w2,
                                                       const float* __restrict__ b2,
                                                       float* __restrict__ out, int N) {
  int node = blockIdx.x * 4 + (threadIdx.x >> 6);
  int lane = threadIdx.x & 63;
  if (node >= N) return;
  int beg = row_ptr[node], end = row_ptr[node + 1];
  if (beg >= end) return;
  ushort4 a4 = ((const ushort4*)(A + (size_t)node * 256))[lane];
  float4 bb = ((const float4*)b1)[lane];
  float4 w = ((const float4*)w2)[lane];
  float a0 = bf2f(a4.x) + bb.x;
  float a1 = bf2f(a4.y) + bb.y;
  float a2 = bf2f(a4.z) + bb.z;
  float a3 = bf2f(a4.w) + bb.w;
  float base = b2[0];
  int2 e0 = eto[beg];
  ushort4 b0 = ((const ushort4*)(Bm + (size_t)e0.x * 256))[lane];
  for (int j = beg + 1; j <= end; ++j) {
    int2 e1 = e0;
    ushort4 bv = b0;
    if (j < end) {
      e1 = eto[j];
      b0 = ((const ushort4*)(Bm + (size_t)e1.x * 256))[lane];
    }
    float h0 = fmaxf(a0 + bf2f(bv.x), 0.f);
    float h1 = fmaxf(a1 + bf2f(bv.y), 0.f);
    float h2 = fmaxf(a2 + bf2f(bv.z), 0.f);
    float h3 = fmaxf(a3 + bf2f(bv.w), 0.f);
    float p = h0 * w.x + h1 * w.y + h2 * w.z + h3 * w.w;
#pragma unroll
    for (int off = 32; off > 0; off >>= 1) p += __shfl_down(p, off, 64);
    if (lane == 0) out[e0.y] = p + base;
    e0 = e1;
  }
}

extern "C" void kernel_launch(void* const* d_in, const int* in_sizes, int n_in,
                              void* d_out, int out_size, void* d_ws, size_t ws_size,
                              hipStream_t stream) {
  const float* x      = (const float*)d_in[0];
  const int*   ei     = (const int*)d_in[1];
  const float* attr   = (const float*)d_in[2];
  const int*   ewi    = (const int*)d_in[3];
  const float* p_pool = (const float*)d_in[4];
  const float* W_ih   = (const float*)d_in[5];
  const float* W_hh   = (const float*)d_in[6];
  const float* b_ih   = (const float*)d_in[7];
  const float* b_hh   = (const float*)d_in[8];
  const float* W_init = (const float*)d_in[9];
  const float* lin1_w = (const float*)d_in[10];
  const float* lin1_b = (const float*)d_in[11];
  const float* lin2_w = (const float*)d_in[12];
  const float* lin2_b = (const float*)d_in[13];
  float* out = (float*)d_out;

  const int C = 256;
  const int N = in_sizes[0] / C;   // 50000
  const int E = in_sizes[2];       // 800000

  // ---- workspace layout (256B aligned) ----
  char* ws = (char*)d_ws;
  size_t off = 0;
  auto alloc = [&](size_t bytes) {
    size_t o = off;
    off = (off + bytes + 255) & ~(size_t)255;
    return o;
  };
  float*          score   = (float*)(ws + alloc((size_t)N * 4));
  float*          pnorm   = (float*)(ws + alloc(4));
  unsigned*       sel     = (unsigned*)(ws + alloc(8));
  int*            ghist   = (int*)(ws + alloc(4096 * 4));
  int*            perm    = (int*)(ws + alloc(C * 4));
  float*          tts     = (float*)(ws + alloc(C * 4));
  float*          xt      = (float*)(ws + alloc((size_t)C * C * 4));
  unsigned short* WevoT   = (unsigned short*)(ws + alloc((size_t)C * C * 2));
  unsigned short* WA      = (unsigned short*)(ws + alloc((size_t)C * C * 2));
  unsigned short* WB      = (unsigned short*)(ws + alloc((size_t)C * C * 2));
  float*          deg     = (float*)(ws + alloc((size_t)N * 4));
  float*          dinv    = (float*)(ws + alloc((size_t)N * 4));
  int*            cnt     = (int*)(ws + alloc((size_t)N * 4));
  int*            rowp    = (int*)(ws + alloc((size_t)(N + 1) * 4));
  int*            cursor  = (int*)(ws + alloc((size_t)N * 4));
  int*            cnt2    = (int*)(ws + alloc((size_t)N * 4));
  int*            rowp2   = (int*)(ws + alloc((size_t)(N + 1) * 4));
  int*            cursor2 = (int*)(ws + alloc((size_t)N * 4));
  int2*           esv     = (int2*)(ws + alloc((size_t)E * 8));
  int2*           eto     = (int2*)(ws + alloc((size_t)E * 8));
  unsigned short* xh      = (unsigned short*)(ws + alloc((size_t)N * C * 2));
  unsigned short* xwh     = (unsigned short*)(ws + alloc((size_t)N * C * 2));
  unsigned short* Bbf     = (unsigned short*)(ws + alloc((size_t)N * C * 2));
  // aliases (stream-ordered producers/consumers):
  unsigned short* ne  = xh;   // xh dead after GEMM1
  unsigned short* Abf = xwh;  // xwh dead after gather

  // 1) score
  pnorm_kernel<<<1, 64, 0, stream>>>(p_pool, pnorm);
  score_kernel<<<(N + 3) / 4, 256, 0, stream>>>(x, p_pool, pnorm, score, N);

  // 2) exact top-256 (12-bit histogram -> bin-floor threshold -> collect+sort)
  zero_kernel<<<4, 256, 0, stream>>>((float4*)ghist, 1024);
  hist12_kernel<<<64, 256, 0, stream>>>(score, N, ghist);
  select12_kernel<<<1, 1024, 0, stream>>>(ghist, C, sel);
  topk_collect_sort<<<1, 1024, 0, stream>>>(score, N, C, sel, perm, tts);

  // 3) x_tilde
  xtilde_kernel<<<C, C, 0, stream>>>(x, perm, tts, xt);

  // 4) GRU -> evolved W (transposed bf16)
  gru_kernel<<<C, C, 0, stream>>>(xt, W_init, W_ih, W_hh, b_ih, b_hh, WevoT);

  // 5) xw = x @ Wevo (bf16 MFMA, bf16 out)
  cast_bf16_kernel<<<(N * C / 4 + 255) / 256, 256, 0, stream>>>(x, xh, N * C / 4);
  mfma_gemm_bf16<<<(N + 63) / 64, 256, 0, stream>>>(xh, WevoT, xwh, N);

  // 6) GCN: merged CSR builds + register gather
  zero_kernel<<<(N / 4 + 255) / 256, 256, 0, stream>>>((float4*)deg, N / 4);
  zero_kernel<<<(N / 4 + 255) / 256, 256, 0, stream>>>((float4*)cnt, N / 4);
  zero_kernel<<<(N / 4 + 255) / 256, 256, 0, stream>>>((float4*)cnt2, N / 4);
  build_hist_kernel<<<(E + 255) / 256, 256, 0, stream>>>(ei, attr, ewi, cnt, deg, cnt2, E);
  dinv_kernel<<<(N + 255) / 256, 256, 0, stream>>>(deg, dinv, N);
  scan_kernel<<<1, 1024, 0, stream>>>(cnt, rowp, cursor, N);
  scan_kernel<<<1, 1024, 0, stream>>>(cnt2, rowp2, cursor2, N);
  csr_fill_merged<<<(E + 255) / 256, 256, 0, stream>>>(ei, attr, dinv, ewi, cursor, cursor2,
                                                       esv, eto, E);
  gcn_gather<<<(N + 3) / 4, 256, 0, stream>>>(xwh, rowp, esv, dinv, ne, N);

  // 7) decoder projections fused (lin1_w rows ARE the B^T layout)
  lin1_cast_kernel<<<(2 * C * C) / 256, 256, 0, stream>>>(lin1_w, WA, WB);
  mfma_gemm_bf16_dual<<<(N + 63) / 64, 256, 0, stream>>>(ne, WA, WB, Abf, Bbf, N);

  // 8) edge decode grouped by src (A-row register-resident)
  edge_decode_csr<<<(N + 3) / 4, 256, 0, stream>>>(Abf, Bbf, rowp2, eto,
                                                   lin1_b, lin2_w, lin2_b, out, N);
}

// Round 6
// 803.990 us; speedup vs baseline: 1.4197x; 1.1966x over previous
//
#include <hip/hip_runtime.h>
#include <hip/hip_bf16.h>
#include <math.h>

// ---------------------------------------------------------------------------
// EvolveGCNH + GCNConv + EdgeDecoder.
// R1: atomic scatter -> dst-CSR register gather (3574 -> 1223 us).
// R3: split-bf16 MFMA GEMMs + bf16 decode operands (1223 -> 1096 us).
// R4: pure-bf16 GEMMs, bf16 xw, src-CSR grouped decode.
// R5: parallel top-k, merged CSR builds, dual GEMM, dbuf rows (962 us;
//     csr_fill_merged now top: 100 MB HBM writes for 12.8 MB payload = 64 B
//     per scattered store, cross-XCD line ping-pong).
// R6: (a) XCD-grouped CSR cursors: per-(node, blockIdx&7) sub-segments so
//         CSR stores stay XCD-local and lines merge in L2;
//     (b) cast of x fused into score_kernel (x read once);
//     (c) single fused zero launch; 2-block scan_dual + parallel
//         totals/cursor kernels.
// ---------------------------------------------------------------------------

typedef __attribute__((ext_vector_type(8))) short bf16x8;
typedef __attribute__((ext_vector_type(4))) float f32x4;

#define NGRP 8

__device__ __forceinline__ unsigned f2key(float f) {
  unsigned u = __float_as_uint(f);
  return (u & 0x80000000u) ? ~u : (u | 0x80000000u);
}

// round-to-nearest-even fp32 -> bf16 bits
__device__ __forceinline__ unsigned short f2bf(float f) {
  unsigned u = __float_as_uint(f);
  unsigned r = u + 0x7fffu + ((u >> 16) & 1u);
  return (unsigned short)(r >> 16);
}
__device__ __forceinline__ float bf2f(unsigned short h) {
  return __uint_as_float((unsigned)h << 16);
}

__global__ void zero_kernel(float4* __restrict__ p, int n4) {
  int i = blockIdx.x * blockDim.x + threadIdx.x;
  if (i < n4) p[i] = make_float4(0.f, 0.f, 0.f, 0.f);
}

__global__ void pnorm_kernel(const float* __restrict__ p, float* __restrict__ out) {
  int lane = threadIdx.x;  // 64 threads
  float4 v = ((const float4*)p)[lane];
  float s = v.x * v.x + v.y * v.y + v.z * v.z + v.w * v.w;
#pragma unroll
  for (int off = 32; off > 0; off >>= 1) s += __shfl_down(s, off, 64);
  if (lane == 0) out[0] = sqrtf(s);
}

// score + bf16 cast of x in one pass (x read once)
__global__ __launch_bounds__(256) void score_cast_kernel(const float* __restrict__ x,
                                                         const float* __restrict__ p,
                                                         const float* __restrict__ pn,
                                                         float* __restrict__ score,
                                                         unsigned short* __restrict__ xh, int N) {
  int node = blockIdx.x * 4 + (threadIdx.x >> 6);
  int lane = threadIdx.x & 63;
  if (node >= N) return;
  float4 xv = ((const float4*)(x + (size_t)node * 256))[lane];
  ushort4 hv;
  hv.x = f2bf(xv.x);
  hv.y = f2bf(xv.y);
  hv.z = f2bf(xv.z);
  hv.w = f2bf(xv.w);
  ((ushort4*)(xh + (size_t)node * 256))[lane] = hv;
  float4 pv = ((const float4*)p)[lane];
  float s = xv.x * pv.x + xv.y * pv.y + xv.z * pv.z + xv.w * pv.w;
#pragma unroll
  for (int off = 32; off > 0; off >>= 1) s += __shfl_down(s, off, 64);
  if (lane == 0) score[node] = s / pn[0];
}

// grid-wide histogram of the top 12 key bits (4096 bins)
__global__ __launch_bounds__(256) void hist12_kernel(const float* __restrict__ score, int n,
                                                     int* __restrict__ gh) {
  __shared__ int lh[4096];
  int tid = threadIdx.x;
  for (int i = tid; i < 4096; i += 256) lh[i] = 0;
  __syncthreads();
  int idx = blockIdx.x * 256 + tid;
  int stride = gridDim.x * 256;
  for (int i = idx; i < n; i += stride) {
    unsigned key = f2key(score[i]);
    atomicAdd(&lh[key >> 20], 1);
  }
  __syncthreads();
  for (int i = tid; i < 4096; i += 256) {
    int v = lh[i];
    if (v) atomicAdd(&gh[i], v);
  }
}

// find highest bin b with suffix-count(b) >= k; sel[0] = bin floor key
__global__ __launch_bounds__(1024) void select12_kernel(const int* __restrict__ gh, int k,
                                                        unsigned* __restrict__ sel) {
  __shared__ int part[1024];
  int tid = threadIdx.x;
  int b0 = tid * 4;
  int s0 = gh[b0], s1 = gh[b0 + 1], s2 = gh[b0 + 2], s3 = gh[b0 + 3];
  part[tid] = s0 + s1 + s2 + s3;
  __syncthreads();
  for (int off = 1; off < 1024; off <<= 1) {
    int v = part[tid];
    int add = (tid + off < 1024) ? part[tid + off] : 0;
    __syncthreads();
    part[tid] = v + add;
    __syncthreads();
  }
  int sufChunk = part[tid];
  int sufNext = (tid < 1023) ? part[tid + 1] : 0;
  if (sufNext < k && sufChunk >= k) {
    int run = sufNext;
    int b;
    run += s3;
    if (run >= k) b = b0 + 3;
    else {
      run += s2;
      if (run >= k) b = b0 + 2;
      else {
        run += s1;
        b = (run >= k) ? b0 + 1 : b0;
      }
    }
    sel[0] = ((unsigned)b) << 20;
  }
}

// Collect all elements with key >= T (bin floor), bitonic sort (key desc,
// idx asc), emit perm[k] and tanh(score) for the top-k.
__global__ __launch_bounds__(1024) void topk_collect_sort(const float* __restrict__ score, int n, int k,
                                                          const unsigned* __restrict__ sel,
                                                          int* __restrict__ perm,
                                                          float* __restrict__ tts) {
  __shared__ unsigned keys[1024];
  __shared__ int idxs[1024];
  __shared__ int cnt;
  int tid = threadIdx.x;
  unsigned T = sel[0];
  if (tid == 0) cnt = 0;
  keys[tid] = 0u;
  idxs[tid] = 0x7fffffff;
  __syncthreads();
  for (int i = tid; i < n; i += 1024) {
    unsigned key = f2key(score[i]);
    if (key >= T) {
      int p = atomicAdd(&cnt, 1);
      if (p < 1024) { keys[p] = key; idxs[p] = i; }
    }
  }
  __syncthreads();
  for (int size = 2; size <= 1024; size <<= 1) {
    for (int stride = size >> 1; stride > 0; stride >>= 1) {
      int j = tid ^ stride;
      if (j > tid) {
        unsigned ka = keys[tid], kb = keys[j];
        int ia = idxs[tid], ib = idxs[j];
        bool aBefore = (ka > kb) || (ka == kb && ia < ib);
        bool up = ((tid & size) == 0);
        if (aBefore != up) {
          keys[tid] = kb; keys[j] = ka;
          idxs[tid] = ib; idxs[j] = ia;
        }
      }
      __syncthreads();
    }
  }
  if (tid < k) {
    int idx = idxs[tid];
    perm[tid] = idx;
    tts[tid] = tanhf(score[idx]);
  }
}

__global__ void xtilde_kernel(const float* __restrict__ x, const int* __restrict__ perm,
                              const float* __restrict__ tts, float* __restrict__ xt) {
  int b = blockIdx.x, t = threadIdx.x;
  xt[b * 256 + t] = x[(size_t)perm[b] * 256 + t] * tts[b];
}

// GRU step; writes evolved W TRANSPOSED as bf16: WevoT[n*256 + k] = bf16(W[k][n])
__global__ __launch_bounds__(256) void gru_kernel(const float* __restrict__ xt,
                                                  const float* __restrict__ Wi,
                                                  const float* __restrict__ W_ih,
                                                  const float* __restrict__ W_hh,
                                                  const float* __restrict__ b_ih,
                                                  const float* __restrict__ b_hh,
                                                  unsigned short* __restrict__ WevoT) {
  int i = blockIdx.x, j = threadIdx.x;  // i = k-row of W, j = n-col
  __shared__ float sx[256], sh[256];
  sx[j] = xt[i * 256 + j];
  sh[j] = Wi[i * 256 + j];
  __syncthreads();
  float gi[3], gh[3];
#pragma unroll
  for (int g = 0; g < 3; ++g) {
    int row = g * 256 + j;
    const float4* wi4 = (const float4*)(W_ih + (size_t)row * 256);
    const float4* wh4 = (const float4*)(W_hh + (size_t)row * 256);
    float si = 0.f, s2 = 0.f;
    for (int k4 = 0; k4 < 64; ++k4) {
      float4 wv = wi4[k4];
      float4 hv = wh4[k4];
      int k = k4 * 4;
      si += sx[k] * wv.x + sx[k + 1] * wv.y + sx[k + 2] * wv.z + sx[k + 3] * wv.w;
      s2 += sh[k] * hv.x + sh[k + 1] * hv.y + sh[k + 2] * hv.z + sh[k + 3] * hv.w;
    }
    gi[g] = si + b_ih[row];
    gh[g] = s2 + b_hh[row];
  }
  float r = 1.f / (1.f + expf(-(gi[0] + gh[0])));
  float z = 1.f / (1.f + expf(-(gi[1] + gh[1])));
  float nn = tanhf(gi[2] + r * gh[2]);
  float w = (1.f - z) * nn + z * sh[j];
  WevoT[(size_t)j * 256 + i] = f2bf(w);
}

// lin1_w [256][512] -> WA/WB bf16 each [256][256] at [n][k] (= B^T layout)
__global__ __launch_bounds__(256) void lin1_cast_kernel(const float* __restrict__ lin1,
                                                        unsigned short* __restrict__ WA,
                                                        unsigned short* __restrict__ WB) {
  int idx = blockIdx.x * 256 + threadIdx.x;  // 131072 total
  int n = idx >> 9, k = idx & 511;
  unsigned short h = f2bf(lin1[idx]);
  if (k < 256)
    WA[n * 256 + k] = h;
  else
    WB[n * 256 + (k - 256)] = h;
}

// ---------------------------------------------------------------------------
// Pure-bf16 MFMA GEMM: C[M,256] = A[M,256] @ B[256,256], bf16 in/out, fp32 acc.
// A row-major bf16; B as B^T rows (BT[n][k]). Layouts HW-verified (R3/R4).
// ---------------------------------------------------------------------------
__global__ __launch_bounds__(256) void mfma_gemm_bf16(const unsigned short* __restrict__ A,
                                                      const unsigned short* __restrict__ BT,
                                                      unsigned short* __restrict__ Cout, int M) {
  int tid = threadIdx.x;
  int wave = tid >> 6, lane = tid & 63;
  int quad = lane >> 4, r16 = lane & 15;
  int n0 = wave * 64;
  int mbase = blockIdx.x * 64;

  f32x4 acc[4][4];
#pragma unroll
  for (int i = 0; i < 4; ++i)
#pragma unroll
    for (int j = 0; j < 4; ++j) acc[i][j] = (f32x4){0.f, 0.f, 0.f, 0.f};

  for (int k0 = 0; k0 < 256; k0 += 32) {
    int koff = k0 + quad * 8;
    bf16x8 af[4], bf[4];
#pragma unroll
    for (int mt = 0; mt < 4; ++mt) {
      int row = mbase + mt * 16 + r16;
      row = row < M ? row : M - 1;
      af[mt] = *(const bf16x8*)(A + (size_t)row * 256 + koff);
    }
#pragma unroll
    for (int nt = 0; nt < 4; ++nt) {
      int nrow = n0 + nt * 16 + r16;
      bf[nt] = *(const bf16x8*)(BT + (size_t)nrow * 256 + koff);
    }
#pragma unroll
    for (int mt = 0; mt < 4; ++mt)
#pragma unroll
      for (int nt = 0; nt < 4; ++nt)
        acc[mt][nt] = __builtin_amdgcn_mfma_f32_16x16x32_bf16(af[mt], bf[nt], acc[mt][nt], 0, 0, 0);
  }
#pragma unroll
  for (int mt = 0; mt < 4; ++mt) {
#pragma unroll
    for (int rr = 0; rr < 4; ++rr) {
      int grow = mbase + mt * 16 + quad * 4 + rr;
      if (grow < M) {
#pragma unroll
        for (int nt = 0; nt < 4; ++nt)
          Cout[(size_t)grow * 256 + n0 + nt * 16 + r16] = f2bf(acc[mt][nt][rr]);
      }
    }
  }
}

// Dual variant: reads A once, produces C1 = A@B1 and C2 = A@B2.
__global__ __launch_bounds__(256) void mfma_gemm_bf16_dual(const unsigned short* __restrict__ A,
                                                           const unsigned short* __restrict__ BT1,
                                                           const unsigned short* __restrict__ BT2,
                                                           unsigned short* __restrict__ C1,
                                                           unsigned short* __restrict__ C2, int M) {
  int tid = threadIdx.x;
  int wave = tid >> 6, lane = tid & 63;
  int quad = lane >> 4, r16 = lane & 15;
  int n0 = wave * 64;
  int mbase = blockIdx.x * 64;

  f32x4 acc1[4][4], acc2[4][4];
#pragma unroll
  for (int i = 0; i < 4; ++i)
#pragma unroll
    for (int j = 0; j < 4; ++j) {
      acc1[i][j] = (f32x4){0.f, 0.f, 0.f, 0.f};
      acc2[i][j] = (f32x4){0.f, 0.f, 0.f, 0.f};
    }

  for (int k0 = 0; k0 < 256; k0 += 32) {
    int koff = k0 + quad * 8;
    bf16x8 af[4], b1[4], b2[4];
#pragma unroll
    for (int mt = 0; mt < 4; ++mt) {
      int row = mbase + mt * 16 + r16;
      row = row < M ? row : M - 1;
      af[mt] = *(const bf16x8*)(A + (size_t)row * 256 + koff);
    }
#pragma unroll
    for (int nt = 0; nt < 4; ++nt) {
      int nrow = n0 + nt * 16 + r16;
      b1[nt] = *(const bf16x8*)(BT1 + (size_t)nrow * 256 + koff);
      b2[nt] = *(const bf16x8*)(BT2 + (size_t)nrow * 256 + koff);
    }
#pragma unroll
    for (int mt = 0; mt < 4; ++mt)
#pragma unroll
      for (int nt = 0; nt < 4; ++nt) {
        acc1[mt][nt] = __builtin_amdgcn_mfma_f32_16x16x32_bf16(af[mt], b1[nt], acc1[mt][nt], 0, 0, 0);
        acc2[mt][nt] = __builtin_amdgcn_mfma_f32_16x16x32_bf16(af[mt], b2[nt], acc2[mt][nt], 0, 0, 0);
      }
  }
#pragma unroll
  for (int mt = 0; mt < 4; ++mt) {
#pragma unroll
    for (int rr = 0; rr < 4; ++rr) {
      int grow = mbase + mt * 16 + quad * 4 + rr;
      if (grow < M) {
#pragma unroll
        for (int nt = 0; nt < 4; ++nt) {
          size_t o = (size_t)grow * 256 + n0 + nt * 16 + r16;
          C1[o] = f2bf(acc1[mt][nt][rr]);
          C2[o] = f2bf(acc2[mt][nt][rr]);
        }
      }
    }
  }
}

// one pass over all edges: per-XCD-group conv-dst count + deg, decoder-src count
__global__ void build_hist_kernel(const int* __restrict__ ei, const float* __restrict__ attr,
                                  const int* __restrict__ ewi,
                                  int* __restrict__ cg1, float* __restrict__ deg,
                                  int* __restrict__ cg2, int E, int N) {
  int e = blockIdx.x * blockDim.x + threadIdx.x;
  int g = blockIdx.x & (NGRP - 1);
  if (e < E) {
    int d = ei[E + e];
    atomicAdd(&cg1[g * N + d], 1);
    atomicAdd(&deg[d], attr[e]);
    atomicAdd(&cg2[g * N + ewi[e]], 1);
  }
}

// parallel over nodes: group-sum totals for both CSRs + dinv
__global__ void node_totals_kernel(const int* __restrict__ cg1, const int* __restrict__ cg2,
                                   const float* __restrict__ deg,
                                   int* __restrict__ tot1, int* __restrict__ tot2,
                                   float* __restrict__ dinv, int N) {
  int i = blockIdx.x * blockDim.x + threadIdx.x;
  if (i >= N) return;
  int s1 = 0, s2 = 0;
#pragma unroll
  for (int g = 0; g < NGRP; ++g) {
    s1 += cg1[g * N + i];
    s2 += cg2[g * N + i];
  }
  tot1[i] = s1;
  tot2[i] = s2;
  float d = deg[i];
  dinv[i] = d > 0.f ? 1.f / sqrtf(d) : 0.f;
}

// 2 blocks: block b scans totb -> rowpb (exclusive prefix + total at [N])
__global__ __launch_bounds__(1024) void scan_dual_kernel(const int* __restrict__ tot1,
                                                         int* __restrict__ rowp1,
                                                         const int* __restrict__ tot2,
                                                         int* __restrict__ rowp2, int N) {
  const int* cnt = (blockIdx.x == 0) ? tot1 : tot2;
  int* row_ptr = (blockIdx.x == 0) ? rowp1 : rowp2;
  __shared__ int ssum[1024];
  int tid = threadIdx.x;
  int chunk = (N + 1023) / 1024;
  int beg = tid * chunk;
  int end = beg + chunk < N ? beg + chunk : N;
  int s = 0;
  for (int i = beg; i < end; ++i) s += cnt[i];
  ssum[tid] = s;
  __syncthreads();
  for (int off = 1; off < 1024; off <<= 1) {
    int v = ssum[tid];
    int add = (tid >= off) ? ssum[tid - off] : 0;
    __syncthreads();
    ssum[tid] = v + add;
    __syncthreads();
  }
  int run = (tid == 0) ? 0 : ssum[tid - 1];
  for (int i = beg; i < end; ++i) {
    row_ptr[i] = run;
    run += cnt[i];
  }
  if (tid == 1023) row_ptr[N] = run;
}

// parallel over nodes: per-(node,group) cursors for both CSRs
__global__ void cursors_kernel(const int* __restrict__ rowp1, const int* __restrict__ cg1,
                               int* __restrict__ cur1,
                               const int* __restrict__ rowp2, const int* __restrict__ cg2,
                               int* __restrict__ cur2, int N) {
  int i = blockIdx.x * blockDim.x + threadIdx.x;
  if (i >= N) return;
  int r1 = rowp1[i];
#pragma unroll
  for (int g = 0; g < NGRP; ++g) {
    cur1[g * N + i] = r1;
    r1 += cg1[g * N + i];
  }
  int r2 = rowp2[i];
#pragma unroll
  for (int g = 0; g < NGRP; ++g) {
    cur2[g * N + i] = r2;
    r2 += cg2[g * N + i];
  }
}

// one pass over all edges: fill both CSRs via XCD-group-private cursors.
// esv[pos] = (src, bits(dinv[src]*attr));  eto[pos2] = (dst, edge_id)
__global__ void csr_fill_merged(const int* __restrict__ ei, const float* __restrict__ attr,
                                const float* __restrict__ dinv, const int* __restrict__ ewi,
                                int* __restrict__ cur1, int* __restrict__ cur2,
                                int2* __restrict__ esv, int2* __restrict__ eto, int E, int N) {
  int e = blockIdx.x * blockDim.x + threadIdx.x;
  int g = blockIdx.x & (NGRP - 1);  // must match build_hist_kernel's mapping
  if (e < E) {
    int s = ei[e], d = ei[E + e];
    int pos = atomicAdd(&cur1[g * N + d], 1);
    esv[pos] = make_int2(s, __float_as_int(dinv[s] * attr[e]));
    int s2 = ewi[e];
    int pos2 = atomicAdd(&cur2[g * N + s2], 1);
    eto[pos2] = make_int2(ewi[E + e], e);
  }
}

// one wave per dst node: fp32 accumulate bf16 xw rows; double-buffered loads
__global__ __launch_bounds__(256) void gcn_gather(const unsigned short* __restrict__ xw,
                                                  const int* __restrict__ row_ptr,
                                                  const int2* __restrict__ esv,
                                                  const float* __restrict__ dinv,
                                                  unsigned short* __restrict__ ne, int N) {
  int node = blockIdx.x * 4 + (threadIdx.x >> 6);
  int lane = threadIdx.x & 63;
  if (node >= N) return;
  int beg = row_ptr[node], end = row_ptr[node + 1];
  float ax = 0.f, ay = 0.f, az = 0.f, aw = 0.f;
  if (beg < end) {
    int2 e0 = esv[beg];
    ushort4 x0 = ((const ushort4*)(xw + (size_t)e0.x * 256))[lane];
    for (int j = beg + 1; j <= end; ++j) {
      int2 e1 = e0;
      ushort4 x1 = x0;
      if (j < end) {
        e1 = esv[j];
        x1 = ((const ushort4*)(xw + (size_t)e1.x * 256))[lane];
      }
      float v = __int_as_float(e0.y);
      ax += bf2f(x0.x) * v;
      ay += bf2f(x0.y) * v;
      az += bf2f(x0.z) * v;
      aw += bf2f(x0.w) * v;
      e0 = e1;
      x0 = x1;
    }
  }
  float dd = dinv[node];
  ushort4 hv;
  hv.x = f2bf(ax * dd);
  hv.y = f2bf(ay * dd);
  hv.z = f2bf(az * dd);
  hv.w = f2bf(aw * dd);
  ((ushort4*)(ne + (size_t)node * 256))[lane] = hv;
}

// decode grouped by src: one wave per src node; A[s]+b1 register-resident,
// stream B[t] double-buffered; scatter pred to original edge order.
__global__ __launch_bounds__(256) void edge_decode_csr(const unsigned short* __restrict__ A,
                                                       const unsigned short* __restrict__ Bm,
                                                       const int* __restrict__ row_ptr,
                                                       const int2* __restrict__ eto,
                                                       const float* __restrict__ b1,
                                                       const float* __restrict__ w2,
                                                       const float* __restrict__ b2,
                                                       float* __restrict__ out, int N) {
  int node = blockIdx.x * 4 + (threadIdx.x >> 6);
  int lane = threadIdx.x & 63;
  if (node >= N) return;
  int beg = row_ptr[node], end = row_ptr[node + 1];
  if (beg >= end) return;
  ushort4 a4 = ((const ushort4*)(A + (size_t)node * 256))[lane];
  float4 bb = ((const float4*)b1)[lane];
  float4 w = ((const float4*)w2)[lane];
  float a0 = bf2f(a4.x) + bb.x;
  float a1 = bf2f(a4.y) + bb.y;
  float a2 = bf2f(a4.z) + bb.z;
  float a3 = bf2f(a4.w) + bb.w;
  float base = b2[0];
  int2 e0 = eto[beg];
  ushort4 b0 = ((const ushort4*)(Bm + (size_t)e0.x * 256))[lane];
  for (int j = beg + 1; j <= end; ++j) {
    int2 e1 = e0;
    ushort4 bv = b0;
    if (j < end) {
      e1 = eto[j];
      b0 = ((const ushort4*)(Bm + (size_t)e1.x * 256))[lane];
    }
    float h0 = fmaxf(a0 + bf2f(bv.x), 0.f);
    float h1 = fmaxf(a1 + bf2f(bv.y), 0.f);
    float h2 = fmaxf(a2 + bf2f(bv.z), 0.f);
    float h3 = fmaxf(a3 + bf2f(bv.w), 0.f);
    float p = h0 * w.x + h1 * w.y + h2 * w.z + h3 * w.w;
#pragma unroll
    for (int off = 32; off > 0; off >>= 1) p += __shfl_down(p, off, 64);
    if (lane == 0) out[e0.y] = p + base;
    e0 = e1;
  }
}

extern "C" void kernel_launch(void* const* d_in, const int* in_sizes, int n_in,
                              void* d_out, int out_size, void* d_ws, size_t ws_size,
                              hipStream_t stream) {
  const float* x      = (const float*)d_in[0];
  const int*   ei     = (const int*)d_in[1];
  const float* attr   = (const float*)d_in[2];
  const int*   ewi    = (const int*)d_in[3];
  const float* p_pool = (const float*)d_in[4];
  const float* W_ih   = (const float*)d_in[5];
  const float* W_hh   = (const float*)d_in[6];
  const float* b_ih   = (const float*)d_in[7];
  const float* b_hh   = (const float*)d_in[8];
  const float* W_init = (const float*)d_in[9];
  const float* lin1_w = (const float*)d_in[10];
  const float* lin1_b = (const float*)d_in[11];
  const float* lin2_w = (const float*)d_in[12];
  const float* lin2_b = (const float*)d_in[13];
  float* out = (float*)d_out;

  const int C = 256;
  const int N = in_sizes[0] / C;   // 50000
  const int E = in_sizes[2];       // 800000

  // ---- workspace layout (256B aligned) ----
  char* ws = (char*)d_ws;
  size_t off = 0;
  auto alloc = [&](size_t bytes) {
    size_t o = off;
    off = (off + bytes + 255) & ~(size_t)255;
    return o;
  };
  float*          score   = (float*)(ws + alloc((size_t)N * 4));
  float*          pnorm   = (float*)(ws + alloc(4));
  unsigned*       sel     = (unsigned*)(ws + alloc(8));
  int*            perm    = (int*)(ws + alloc(C * 4));
  float*          tts     = (float*)(ws + alloc(C * 4));
  float*          xt      = (float*)(ws + alloc((size_t)C * C * 4));
  unsigned short* WevoT   = (unsigned short*)(ws + alloc((size_t)C * C * 2));
  unsigned short* WA      = (unsigned short*)(ws + alloc((size_t)C * C * 2));
  unsigned short* WB      = (unsigned short*)(ws + alloc((size_t)C * C * 2));
  // contiguous zero region: deg | cg1 | cg2 | ghist
  int   zeroInts = N + 2 * NGRP * N + 4096;
  char* zbase    = ws + alloc((size_t)zeroInts * 4);
  float* deg   = (float*)zbase;
  int*   cg1   = (int*)(zbase + (size_t)N * 4);
  int*   cg2   = (int*)(zbase + (size_t)N * 4 + (size_t)NGRP * N * 4);
  int*   ghist = (int*)(zbase + (size_t)N * 4 + (size_t)2 * NGRP * N * 4);
  float*          dinv    = (float*)(ws + alloc((size_t)N * 4));
  int*            tot1    = (int*)(ws + alloc((size_t)N * 4));
  int*            tot2    = (int*)(ws + alloc((size_t)N * 4));
  int*            rowp1   = (int*)(ws + alloc((size_t)(N + 1) * 4));
  int*            rowp2   = (int*)(ws + alloc((size_t)(N + 1) * 4));
  int*            cur1    = (int*)(ws + alloc((size_t)NGRP * N * 4));
  int*            cur2    = (int*)(ws + alloc((size_t)NGRP * N * 4));
  int2*           esv     = (int2*)(ws + alloc((size_t)E * 8));
  int2*           eto     = (int2*)(ws + alloc((size_t)E * 8));
  unsigned short* xh      = (unsigned short*)(ws + alloc((size_t)N * C * 2));
  unsigned short* xwh     = (unsigned short*)(ws + alloc((size_t)N * C * 2));
  unsigned short* Bbf     = (unsigned short*)(ws + alloc((size_t)N * C * 2));
  // aliases (stream-ordered producers/consumers):
  unsigned short* ne  = xh;   // xh dead after GEMM1
  unsigned short* Abf = xwh;  // xwh dead after gather

  // 0) zero deg/cg1/cg2/ghist in one launch
  zero_kernel<<<(zeroInts / 4 + 255) / 256, 256, 0, stream>>>((float4*)zbase, zeroInts / 4);

  // 1) score + bf16 cast of x (single pass over x)
  pnorm_kernel<<<1, 64, 0, stream>>>(p_pool, pnorm);
  score_cast_kernel<<<(N + 3) / 4, 256, 0, stream>>>(x, p_pool, pnorm, score, xh, N);

  // 2) exact top-256 (12-bit histogram -> bin-floor threshold -> collect+sort)
  hist12_kernel<<<64, 256, 0, stream>>>(score, N, ghist);
  select12_kernel<<<1, 1024, 0, stream>>>(ghist, C, sel);
  topk_collect_sort<<<1, 1024, 0, stream>>>(score, N, C, sel, perm, tts);

  // 3) x_tilde
  xtilde_kernel<<<C, C, 0, stream>>>(x, perm, tts, xt);

  // 4) GRU -> evolved W (transposed bf16)
  gru_kernel<<<C, C, 0, stream>>>(xt, W_init, W_ih, W_hh, b_ih, b_hh, WevoT);

  // 5) xw = x @ Wevo (bf16 MFMA, bf16 out)
  mfma_gemm_bf16<<<(N + 63) / 64, 256, 0, stream>>>(xh, WevoT, xwh, N);

  // 6) GCN: XCD-grouped CSR builds + register gather
  build_hist_kernel<<<(E + 255) / 256, 256, 0, stream>>>(ei, attr, ewi, cg1, deg, cg2, E, N);
  node_totals_kernel<<<(N + 255) / 256, 256, 0, stream>>>(cg1, cg2, deg, tot1, tot2, dinv, N);
  scan_dual_kernel<<<2, 1024, 0, stream>>>(tot1, rowp1, tot2, rowp2, N);
  cursors_kernel<<<(N + 255) / 256, 256, 0, stream>>>(rowp1, cg1, cur1, rowp2, cg2, cur2, N);
  csr_fill_merged<<<(E + 255) / 256, 256, 0, stream>>>(ei, attr, dinv, ewi, cur1, cur2,
                                                       esv, eto, E, N);
  gcn_gather<<<(N + 3) / 4, 256, 0, stream>>>(xwh, rowp1, esv, dinv, ne, N);

  // 7) decoder projections fused (lin1_w rows ARE the B^T layout)
  lin1_cast_kernel<<<(2 * C * C) / 256, 256, 0, stream>>>(lin1_w, WA, WB);
  mfma_gemm_bf16_dual<<<(N + 63) / 64, 256, 0, stream>>>(ne, WA, WB, Abf, Bbf, N);

  // 8) edge decode grouped by src (A-row register-resident)
  edge_decode_csr<<<(N + 3) / 4, 256, 0, stream>>>(Abf, Bbf, rowp2, eto,
                                                   lin1_b, lin2_w, lin2_b, out, N);
}

// Round 7
// 608.789 us; speedup vs baseline: 1.8749x; 1.3206x over previous
//
#include <hip/hip_runtime.h>
#include <hip/hip_bf16.h>
#include <math.h>

// ---------------------------------------------------------------------------
// EvolveGCNH + GCNConv + EdgeDecoder.
// R1: atomic scatter -> dst-CSR register gather (3574 -> 1223 us).
// R3: split-bf16 MFMA GEMMs + bf16 decode operands.
// R4: pure-bf16 GEMMs, bf16 xw, src-CSR grouped decode.
// R5: parallel top-k, merged CSR builds, dual GEMM (962 us).
// R6: XCD-grouped cursors FAILED (WRITE_SIZE 100->97 MB): sub-segments
//     interleave within cache lines, cross-XCD partial-line ping-pong remains.
// R7: two-phase bucket sort for both CSRs:
//     p0: 98-bucket histogram (node>>9) + 1-block scan;
//     p1: tile-ranked scatter -> per-(block,bucket) contiguous runs, so every
//         line is written by one block/XCD (write amp ~1x);
//     p2: one block per bucket: LDS node-histogram + deg accumulation + scan,
//         writes rowp/dinv/final CSR into an L2-local 64KB window.
//     Eliminates build_hist's 2.4M global atomics + csr_fill's 97MB writes.
// ---------------------------------------------------------------------------

typedef __attribute__((ext_vector_type(8))) short bf16x8;
typedef __attribute__((ext_vector_type(4))) float f32x4;

#define WSHIFT 9              // 512 nodes per bucket
#define WMASK 511
#define NBUCK 98              // ceil(50000/512)

__device__ __forceinline__ unsigned f2key(float f) {
  unsigned u = __float_as_uint(f);
  return (u & 0x80000000u) ? ~u : (u | 0x80000000u);
}

// round-to-nearest-even fp32 -> bf16 bits
__device__ __forceinline__ unsigned short f2bf(float f) {
  unsigned u = __float_as_uint(f);
  unsigned r = u + 0x7fffu + ((u >> 16) & 1u);
  return (unsigned short)(r >> 16);
}
__device__ __forceinline__ float bf2f(unsigned short h) {
  return __uint_as_float((unsigned)h << 16);
}

__global__ void zero_kernel(float4* __restrict__ p, int n4) {
  int i = blockIdx.x * blockDim.x + threadIdx.x;
  if (i < n4) p[i] = make_float4(0.f, 0.f, 0.f, 0.f);
}

__global__ void pnorm_kernel(const float* __restrict__ p, float* __restrict__ out) {
  int lane = threadIdx.x;  // 64 threads
  float4 v = ((const float4*)p)[lane];
  float s = v.x * v.x + v.y * v.y + v.z * v.z + v.w * v.w;
#pragma unroll
  for (int off = 32; off > 0; off >>= 1) s += __shfl_down(s, off, 64);
  if (lane == 0) out[0] = sqrtf(s);
}

// score + bf16 cast of x in one pass (x read once)
__global__ __launch_bounds__(256) void score_cast_kernel(const float* __restrict__ x,
                                                         const float* __restrict__ p,
                                                         const float* __restrict__ pn,
                                                         float* __restrict__ score,
                                                         unsigned short* __restrict__ xh, int N) {
  int node = blockIdx.x * 4 + (threadIdx.x >> 6);
  int lane = threadIdx.x & 63;
  if (node >= N) return;
  float4 xv = ((const float4*)(x + (size_t)node * 256))[lane];
  ushort4 hv;
  hv.x = f2bf(xv.x);
  hv.y = f2bf(xv.y);
  hv.z = f2bf(xv.z);
  hv.w = f2bf(xv.w);
  ((ushort4*)(xh + (size_t)node * 256))[lane] = hv;
  float4 pv = ((const float4*)p)[lane];
  float s = xv.x * pv.x + xv.y * pv.y + xv.z * pv.z + xv.w * pv.w;
#pragma unroll
  for (int off = 32; off > 0; off >>= 1) s += __shfl_down(s, off, 64);
  if (lane == 0) score[node] = s / pn[0];
}

// grid-wide histogram of the top 12 key bits (4096 bins)
__global__ __launch_bounds__(256) void hist12_kernel(const float* __restrict__ score, int n,
                                                     int* __restrict__ gh) {
  __shared__ int lh[4096];
  int tid = threadIdx.x;
  for (int i = tid; i < 4096; i += 256) lh[i] = 0;
  __syncthreads();
  int idx = blockIdx.x * 256 + tid;
  int stride = gridDim.x * 256;
  for (int i = idx; i < n; i += stride) {
    unsigned key = f2key(score[i]);
    atomicAdd(&lh[key >> 20], 1);
  }
  __syncthreads();
  for (int i = tid; i < 4096; i += 256) {
    int v = lh[i];
    if (v) atomicAdd(&gh[i], v);
  }
}

// find highest bin b with suffix-count(b) >= k; sel[0] = bin floor key
__global__ __launch_bounds__(1024) void select12_kernel(const int* __restrict__ gh, int k,
                                                        unsigned* __restrict__ sel) {
  __shared__ int part[1024];
  int tid = threadIdx.x;
  int b0 = tid * 4;
  int s0 = gh[b0], s1 = gh[b0 + 1], s2 = gh[b0 + 2], s3 = gh[b0 + 3];
  part[tid] = s0 + s1 + s2 + s3;
  __syncthreads();
  for (int off = 1; off < 1024; off <<= 1) {
    int v = part[tid];
    int add = (tid + off < 1024) ? part[tid + off] : 0;
    __syncthreads();
    part[tid] = v + add;
    __syncthreads();
  }
  int sufChunk = part[tid];
  int sufNext = (tid < 1023) ? part[tid + 1] : 0;
  if (sufNext < k && sufChunk >= k) {
    int run = sufNext;
    int b;
    run += s3;
    if (run >= k) b = b0 + 3;
    else {
      run += s2;
      if (run >= k) b = b0 + 2;
      else {
        run += s1;
        b = (run >= k) ? b0 + 1 : b0;
      }
    }
    sel[0] = ((unsigned)b) << 20;
  }
}

// Collect all elements with key >= T (bin floor), bitonic sort (key desc,
// idx asc), emit perm[k] and tanh(score) for the top-k.
__global__ __launch_bounds__(1024) void topk_collect_sort(const float* __restrict__ score, int n, int k,
                                                          const unsigned* __restrict__ sel,
                                                          int* __restrict__ perm,
                                                          float* __restrict__ tts) {
  __shared__ unsigned keys[1024];
  __shared__ int idxs[1024];
  __shared__ int cnt;
  int tid = threadIdx.x;
  unsigned T = sel[0];
  if (tid == 0) cnt = 0;
  keys[tid] = 0u;
  idxs[tid] = 0x7fffffff;
  __syncthreads();
  for (int i = tid; i < n; i += 1024) {
    unsigned key = f2key(score[i]);
    if (key >= T) {
      int p = atomicAdd(&cnt, 1);
      if (p < 1024) { keys[p] = key; idxs[p] = i; }
    }
  }
  __syncthreads();
  for (int size = 2; size <= 1024; size <<= 1) {
    for (int stride = size >> 1; stride > 0; stride >>= 1) {
      int j = tid ^ stride;
      if (j > tid) {
        unsigned ka = keys[tid], kb = keys[j];
        int ia = idxs[tid], ib = idxs[j];
        bool aBefore = (ka > kb) || (ka == kb && ia < ib);
        bool up = ((tid & size) == 0);
        if (aBefore != up) {
          keys[tid] = kb; keys[j] = ka;
          idxs[tid] = ib; idxs[j] = ia;
        }
      }
      __syncthreads();
    }
  }
  if (tid < k) {
    int idx = idxs[tid];
    perm[tid] = idx;
    tts[tid] = tanhf(score[idx]);
  }
}

__global__ void xtilde_kernel(const float* __restrict__ x, const int* __restrict__ perm,
                              const float* __restrict__ tts, float* __restrict__ xt) {
  int b = blockIdx.x, t = threadIdx.x;
  xt[b * 256 + t] = x[(size_t)perm[b] * 256 + t] * tts[b];
}

// GRU step; writes evolved W TRANSPOSED as bf16: WevoT[n*256 + k] = bf16(W[k][n])
__global__ __launch_bounds__(256) void gru_kernel(const float* __restrict__ xt,
                                                  const float* __restrict__ Wi,
                                                  const float* __restrict__ W_ih,
                                                  const float* __restrict__ W_hh,
                                                  const float* __restrict__ b_ih,
                                                  const float* __restrict__ b_hh,
                                                  unsigned short* __restrict__ WevoT) {
  int i = blockIdx.x, j = threadIdx.x;  // i = k-row of W, j = n-col
  __shared__ float sx[256], sh[256];
  sx[j] = xt[i * 256 + j];
  sh[j] = Wi[i * 256 + j];
  __syncthreads();
  float gi[3], gh[3];
#pragma unroll
  for (int g = 0; g < 3; ++g) {
    int row = g * 256 + j;
    const float4* wi4 = (const float4*)(W_ih + (size_t)row * 256);
    const float4* wh4 = (const float4*)(W_hh + (size_t)row * 256);
    float si = 0.f, s2 = 0.f;
    for (int k4 = 0; k4 < 64; ++k4) {
      float4 wv = wi4[k4];
      float4 hv = wh4[k4];
      int k = k4 * 4;
      si += sx[k] * wv.x + sx[k + 1] * wv.y + sx[k + 2] * wv.z + sx[k + 3] * wv.w;
      s2 += sh[k] * hv.x + sh[k + 1] * hv.y + sh[k + 2] * hv.z + sh[k + 3] * hv.w;
    }
    gi[g] = si + b_ih[row];
    gh[g] = s2 + b_hh[row];
  }
  float r = 1.f / (1.f + expf(-(gi[0] + gh[0])));
  float z = 1.f / (1.f + expf(-(gi[1] + gh[1])));
  float nn = tanhf(gi[2] + r * gh[2]);
  float w = (1.f - z) * nn + z * sh[j];
  WevoT[(size_t)j * 256 + i] = f2bf(w);
}

// lin1_w [256][512] -> WA/WB bf16 each [256][256] at [n][k] (= B^T layout)
__global__ __launch_bounds__(256) void lin1_cast_kernel(const float* __restrict__ lin1,
                                                        unsigned short* __restrict__ WA,
                                                        unsigned short* __restrict__ WB) {
  int idx = blockIdx.x * 256 + threadIdx.x;  // 131072 total
  int n = idx >> 9, k = idx & 511;
  unsigned short h = f2bf(lin1[idx]);
  if (k < 256)
    WA[n * 256 + k] = h;
  else
    WB[n * 256 + (k - 256)] = h;
}

// ---------------------------------------------------------------------------
// Pure-bf16 MFMA GEMM: C[M,256] = A[M,256] @ B[256,256], bf16 in/out, fp32 acc.
// A row-major bf16; B as B^T rows (BT[n][k]). Layouts HW-verified (R3/R4).
// ---------------------------------------------------------------------------
__global__ __launch_bounds__(256) void mfma_gemm_bf16(const unsigned short* __restrict__ A,
                                                      const unsigned short* __restrict__ BT,
                                                      unsigned short* __restrict__ Cout, int M) {
  int tid = threadIdx.x;
  int wave = tid >> 6, lane = tid & 63;
  int quad = lane >> 4, r16 = lane & 15;
  int n0 = wave * 64;
  int mbase = blockIdx.x * 64;

  f32x4 acc[4][4];
#pragma unroll
  for (int i = 0; i < 4; ++i)
#pragma unroll
    for (int j = 0; j < 4; ++j) acc[i][j] = (f32x4){0.f, 0.f, 0.f, 0.f};

  for (int k0 = 0; k0 < 256; k0 += 32) {
    int koff = k0 + quad * 8;
    bf16x8 af[4], bf[4];
#pragma unroll
    for (int mt = 0; mt < 4; ++mt) {
      int row = mbase + mt * 16 + r16;
      row = row < M ? row : M - 1;
      af[mt] = *(const bf16x8*)(A + (size_t)row * 256 + koff);
    }
#pragma unroll
    for (int nt = 0; nt < 4; ++nt) {
      int nrow = n0 + nt * 16 + r16;
      bf[nt] = *(const bf16x8*)(BT + (size_t)nrow * 256 + koff);
    }
#pragma unroll
    for (int mt = 0; mt < 4; ++mt)
#pragma unroll
      for (int nt = 0; nt < 4; ++nt)
        acc[mt][nt] = __builtin_amdgcn_mfma_f32_16x16x32_bf16(af[mt], bf[nt], acc[mt][nt], 0, 0, 0);
  }
#pragma unroll
  for (int mt = 0; mt < 4; ++mt) {
#pragma unroll
    for (int rr = 0; rr < 4; ++rr) {
      int grow = mbase + mt * 16 + quad * 4 + rr;
      if (grow < M) {
#pragma unroll
        for (int nt = 0; nt < 4; ++nt)
          Cout[(size_t)grow * 256 + n0 + nt * 16 + r16] = f2bf(acc[mt][nt][rr]);
      }
    }
  }
}

// Dual variant: reads A once, produces C1 = A@B1 and C2 = A@B2.
__global__ __launch_bounds__(256) void mfma_gemm_bf16_dual(const unsigned short* __restrict__ A,
                                                           const unsigned short* __restrict__ BT1,
                                                           const unsigned short* __restrict__ BT2,
                                                           unsigned short* __restrict__ C1,
                                                           unsigned short* __restrict__ C2, int M) {
  int tid = threadIdx.x;
  int wave = tid >> 6, lane = tid & 63;
  int quad = lane >> 4, r16 = lane & 15;
  int n0 = wave * 64;
  int mbase = blockIdx.x * 64;

  f32x4 acc1[4][4], acc2[4][4];
#pragma unroll
  for (int i = 0; i < 4; ++i)
#pragma unroll
    for (int j = 0; j < 4; ++j) {
      acc1[i][j] = (f32x4){0.f, 0.f, 0.f, 0.f};
      acc2[i][j] = (f32x4){0.f, 0.f, 0.f, 0.f};
    }

  for (int k0 = 0; k0 < 256; k0 += 32) {
    int koff = k0 + quad * 8;
    bf16x8 af[4], b1[4], b2[4];
#pragma unroll
    for (int mt = 0; mt < 4; ++mt) {
      int row = mbase + mt * 16 + r16;
      row = row < M ? row : M - 1;
      af[mt] = *(const bf16x8*)(A + (size_t)row * 256 + koff);
    }
#pragma unroll
    for (int nt = 0; nt < 4; ++nt) {
      int nrow = n0 + nt * 16 + r16;
      b1[nt] = *(const bf16x8*)(BT1 + (size_t)nrow * 256 + koff);
      b2[nt] = *(const bf16x8*)(BT2 + (size_t)nrow * 256 + koff);
    }
#pragma unroll
    for (int mt = 0; mt < 4; ++mt)
#pragma unroll
      for (int nt = 0; nt < 4; ++nt) {
        acc1[mt][nt] = __builtin_amdgcn_mfma_f32_16x16x32_bf16(af[mt], b1[nt], acc1[mt][nt], 0, 0, 0);
        acc2[mt][nt] = __builtin_amdgcn_mfma_f32_16x16x32_bf16(af[mt], b2[nt], acc2[mt][nt], 0, 0, 0);
      }
  }
#pragma unroll
  for (int mt = 0; mt < 4; ++mt) {
#pragma unroll
    for (int rr = 0; rr < 4; ++rr) {
      int grow = mbase + mt * 16 + quad * 4 + rr;
      if (grow < M) {
#pragma unroll
        for (int nt = 0; nt < 4; ++nt) {
          size_t o = (size_t)grow * 256 + n0 + nt * 16 + r16;
          C1[o] = f2bf(acc1[mt][nt][rr]);
          C2[o] = f2bf(acc2[mt][nt][rr]);
        }
      }
    }
  }
}

// ---- two-phase bucket sort for both CSRs -----------------------------------

// phase 0: bucket histogram for conv-dst and decoder-src (LDS-aggregated)
__global__ __launch_bounds__(256) void bucket_hist_kernel(const int* __restrict__ ei,
                                                          const int* __restrict__ ewi,
                                                          int* __restrict__ bcnt1,
                                                          int* __restrict__ bcnt2, int E) {
  __shared__ int c1[128], c2[128];
  int tid = threadIdx.x;
  if (tid < 128) { c1[tid] = 0; c2[tid] = 0; }
  __syncthreads();
  int idx = blockIdx.x * 256 + tid;
  int stride = gridDim.x * 256;
  for (int e = idx; e < E; e += stride) {
    atomicAdd(&c1[ei[E + e] >> WSHIFT], 1);
    atomicAdd(&c2[ewi[e] >> WSHIFT], 1);
  }
  __syncthreads();
  if (tid < 128) {
    if (c1[tid]) atomicAdd(&bcnt1[tid], c1[tid]);
    if (c2[tid]) atomicAdd(&bcnt2[tid], c2[tid]);
  }
}

// phase 0b: scan bucket counts -> bases + cursors; also rowp[N] = E
__global__ __launch_bounds__(128) void bucket_scan_kernel(const int* __restrict__ bcnt1,
                                                          const int* __restrict__ bcnt2,
                                                          int* __restrict__ bbase1,
                                                          int* __restrict__ bbase2,
                                                          int* __restrict__ gcur1,
                                                          int* __restrict__ gcur2,
                                                          int* __restrict__ rowp1,
                                                          int* __restrict__ rowp2, int N, int E) {
  __shared__ int ss[128];
  int tid = threadIdx.x;
  // CSR 1
  int v = (tid < NBUCK) ? bcnt1[tid] : 0;
  ss[tid] = v;
  __syncthreads();
  for (int off = 1; off < 128; off <<= 1) {
    int a = ss[tid];
    int b = (tid >= off) ? ss[tid - off] : 0;
    __syncthreads();
    ss[tid] = a + b;
    __syncthreads();
  }
  int excl = ss[tid] - v;
  if (tid < NBUCK) { bbase1[tid] = excl; gcur1[tid] = excl; }
  if (tid == NBUCK - 1) bbase1[NBUCK] = excl + v;
  __syncthreads();
  // CSR 2
  v = (tid < NBUCK) ? bcnt2[tid] : 0;
  ss[tid] = v;
  __syncthreads();
  for (int off = 1; off < 128; off <<= 1) {
    int a = ss[tid];
    int b = (tid >= off) ? ss[tid - off] : 0;
    __syncthreads();
    ss[tid] = a + b;
    __syncthreads();
  }
  excl = ss[tid] - v;
  if (tid < NBUCK) { bbase2[tid] = excl; gcur2[tid] = excl; }
  if (tid == NBUCK - 1) bbase2[NBUCK] = excl + v;
  if (tid == 0) { rowp1[N] = E; rowp2[N] = E; }
}

// phase 1 (conv): tile-ranked scatter into bucket staging.
// stage.x = src | (dstLocal<<16), stage.y = attr bits
__global__ __launch_bounds__(256) void p1_conv_kernel(const int* __restrict__ ei,
                                                      const float* __restrict__ attr,
                                                      int* __restrict__ gcur,
                                                      int2* __restrict__ stage, int E) {
  __shared__ int cnt[128], cur[128];
  int tid = threadIdx.x;
  int base = blockIdx.x * 4096;
  if (tid < 128) cnt[tid] = 0;
  __syncthreads();
  int bk[16];
  int2 pl[16];
#pragma unroll
  for (int i = 0; i < 16; ++i) {
    int e = base + i * 256 + tid;
    bk[i] = -1;
    if (e < E) {
      int d = ei[E + e];
      int s = ei[e];
      bk[i] = d >> WSHIFT;
      pl[i] = make_int2(s | ((d & WMASK) << 16), __float_as_int(attr[e]));
      atomicAdd(&cnt[bk[i]], 1);
    }
  }
  __syncthreads();
  if (tid < NBUCK) {
    int c = cnt[tid];
    cur[tid] = c ? atomicAdd(&gcur[tid], c) : 0;
  }
  __syncthreads();
#pragma unroll
  for (int i = 0; i < 16; ++i) {
    if (bk[i] >= 0) {
      int pos = atomicAdd(&cur[bk[i]], 1);
      stage[pos] = pl[i];
    }
  }
}

// phase 1 (decoder): stage.x = dst | (srcLocal<<16), stage.y = edge_id
__global__ __launch_bounds__(256) void p1_dec_kernel(const int* __restrict__ ewi,
                                                     int* __restrict__ gcur,
                                                     int2* __restrict__ stage, int E) {
  __shared__ int cnt[128], cur[128];
  int tid = threadIdx.x;
  int base = blockIdx.x * 4096;
  if (tid < 128) cnt[tid] = 0;
  __syncthreads();
  int bk[16];
  int2 pl[16];
#pragma unroll
  for (int i = 0; i < 16; ++i) {
    int e = base + i * 256 + tid;
    bk[i] = -1;
    if (e < E) {
      int s = ewi[e];
      int d = ewi[E + e];
      bk[i] = s >> WSHIFT;
      pl[i] = make_int2(d | ((s & WMASK) << 16), e);
      atomicAdd(&cnt[bk[i]], 1);
    }
  }
  __syncthreads();
  if (tid < NBUCK) {
    int c = cnt[tid];
    cur[tid] = c ? atomicAdd(&gcur[tid], c) : 0;
  }
  __syncthreads();
#pragma unroll
  for (int i = 0; i < 16; ++i) {
    if (bk[i] >= 0) {
      int pos = atomicAdd(&cur[bk[i]], 1);
      stage[pos] = pl[i];
    }
  }
}

// phase 2 (conv): one block per bucket. LDS node-histogram + deg accumulation,
// LDS scan -> rowp/dinv/final CSR (node-ordered). esv.x = src, esv.y = attr.
__global__ __launch_bounds__(256) void p2_conv_kernel(const int2* __restrict__ stage,
                                                      const int* __restrict__ bbase,
                                                      int2* __restrict__ esv,
                                                      int* __restrict__ rowp,
                                                      float* __restrict__ dinv, int N) {
  __shared__ int cnt[512];
  __shared__ float degs[512];
  __shared__ int pref[512];
  __shared__ int ss[256];
  int tid = threadIdx.x;
  int b = blockIdx.x;
  int beg = bbase[b], end = bbase[b + 1];
  int node0 = b << WSHIFT;
  cnt[tid] = 0; cnt[tid + 256] = 0;
  degs[tid] = 0.f; degs[tid + 256] = 0.f;
  __syncthreads();
  for (int j = beg + tid; j < end; j += 256) {
    int2 p = stage[j];
    int loc = p.x >> 16;
    atomicAdd(&cnt[loc], 1);
    atomicAdd(&degs[loc], __int_as_float(p.y));
  }
  __syncthreads();
  // exclusive scan over 512 bins (each thread owns 2 consecutive)
  int c0 = cnt[2 * tid], c1 = cnt[2 * tid + 1];
  ss[tid] = c0 + c1;
  __syncthreads();
  for (int off = 1; off < 256; off <<= 1) {
    int a = ss[tid];
    int bb = (tid >= off) ? ss[tid - off] : 0;
    __syncthreads();
    ss[tid] = a + bb;
    __syncthreads();
  }
  int excl = (tid ? ss[tid - 1] : 0);
  pref[2 * tid] = excl;
  pref[2 * tid + 1] = excl + c0;
  __syncthreads();
  // write rowp + dinv for this bucket's nodes
#pragma unroll
  for (int h = 0; h < 2; ++h) {
    int i = tid + h * 256;
    int node = node0 + i;
    if (node < N) {
      rowp[node] = beg + pref[i];
      float d = degs[i];
      dinv[node] = d > 0.f ? 1.f / sqrtf(d) : 0.f;
    }
  }
  __syncthreads();
  // scatter into final node-ordered positions (L2-local window)
  for (int j = beg + tid; j < end; j += 256) {
    int2 p = stage[j];
    int loc = p.x >> 16;
    int pos = beg + atomicAdd(&pref[loc], 1);
    esv[pos] = make_int2(p.x & 0xFFFF, p.y);
  }
}

// phase 2 (decoder): same minus deg. eto.x = dst, eto.y = edge_id.
__global__ __launch_bounds__(256) void p2_dec_kernel(const int2* __restrict__ stage,
                                                     const int* __restrict__ bbase,
                                                     int2* __restrict__ eto,
                                                     int* __restrict__ rowp, int N) {
  __shared__ int cnt[512];
  __shared__ int pref[512];
  __shared__ int ss[256];
  int tid = threadIdx.x;
  int b = blockIdx.x;
  int beg = bbase[b], end = bbase[b + 1];
  int node0 = b << WSHIFT;
  cnt[tid] = 0; cnt[tid + 256] = 0;
  __syncthreads();
  for (int j = beg + tid; j < end; j += 256) {
    int2 p = stage[j];
    atomicAdd(&cnt[p.x >> 16], 1);
  }
  __syncthreads();
  int c0 = cnt[2 * tid], c1 = cnt[2 * tid + 1];
  ss[tid] = c0 + c1;
  __syncthreads();
  for (int off = 1; off < 256; off <<= 1) {
    int a = ss[tid];
    int bb = (tid >= off) ? ss[tid - off] : 0;
    __syncthreads();
    ss[tid] = a + bb;
    __syncthreads();
  }
  int excl = (tid ? ss[tid - 1] : 0);
  pref[2 * tid] = excl;
  pref[2 * tid + 1] = excl + c0;
  __syncthreads();
#pragma unroll
  for (int h = 0; h < 2; ++h) {
    int i = tid + h * 256;
    int node = node0 + i;
    if (node < N) rowp[node] = beg + pref[i];
  }
  __syncthreads();
  for (int j = beg + tid; j < end; j += 256) {
    int2 p = stage[j];
    int loc = p.x >> 16;
    int pos = beg + atomicAdd(&pref[loc], 1);
    eto[pos] = make_int2(p.x & 0xFFFF, p.y);
  }
}

// one wave per dst node: fp32 accumulate bf16 xw rows; double-buffered loads.
// esv.y = attr bits; value = dinv[src] * attr (dinv L2-resident broadcast).
__global__ __launch_bounds__(256) void gcn_gather(const unsigned short* __restrict__ xw,
                                                  const int* __restrict__ row_ptr,
                                                  const int2* __restrict__ esv,
                                                  const float* __restrict__ dinv,
                                                  unsigned short* __restrict__ ne, int N) {
  int node = blockIdx.x * 4 + (threadIdx.x >> 6);
  int lane = threadIdx.x & 63;
  if (node >= N) return;
  int beg = row_ptr[node], end = row_ptr[node + 1];
  float ax = 0.f, ay = 0.f, az = 0.f, aw = 0.f;
  if (beg < end) {
    int2 e0 = esv[beg];
    ushort4 x0 = ((const ushort4*)(xw + (size_t)e0.x * 256))[lane];
    float v0 = dinv[e0.x] * __int_as_float(e0.y);
    for (int j = beg + 1; j <= end; ++j) {
      ushort4 xc = x0;
      float vc = v0;
      if (j < end) {
        int2 e1 = esv[j];
        x0 = ((const ushort4*)(xw + (size_t)e1.x * 256))[lane];
        v0 = dinv[e1.x] * __int_as_float(e1.y);
      }
      ax += bf2f(xc.x) * vc;
      ay += bf2f(xc.y) * vc;
      az += bf2f(xc.z) * vc;
      aw += bf2f(xc.w) * vc;
    }
  }
  float dd = dinv[node];
  ushort4 hv;
  hv.x = f2bf(ax * dd);
  hv.y = f2bf(ay * dd);
  hv.z = f2bf(az * dd);
  hv.w = f2bf(aw * dd);
  ((ushort4*)(ne + (size_t)node * 256))[lane] = hv;
}

// decode grouped by src: one wave per src node; A[s]+b1 register-resident,
// stream B[t] double-buffered; scatter pred to original edge order.
__global__ __launch_bounds__(256) void edge_decode_csr(const unsigned short* __restrict__ A,
                                                       const unsigned short* __restrict__ Bm,
                                                       const int* __restrict__ row_ptr,
                                                       const int2* __restrict__ eto,
                                                       const float* __restrict__ b1,
                                                       const float* __restrict__ w2,
                                                       const float* __restrict__ b2,
                                                       float* __restrict__ out, int N) {
  int node = blockIdx.x * 4 + (threadIdx.x >> 6);
  int lane = threadIdx.x & 63;
  if (node >= N) return;
  int beg = row_ptr[node], end = row_ptr[node + 1];
  if (beg >= end) return;
  ushort4 a4 = ((const ushort4*)(A + (size_t)node * 256))[lane];
  float4 bb = ((const float4*)b1)[lane];
  float4 w = ((const float4*)w2)[lane];
  float a0 = bf2f(a4.x) + bb.x;
  float a1 = bf2f(a4.y) + bb.y;
  float a2 = bf2f(a4.z) + bb.z;
  float a3 = bf2f(a4.w) + bb.w;
  float base = b2[0];
  int2 e0 = eto[beg];
  ushort4 b0 = ((const ushort4*)(Bm + (size_t)e0.x * 256))[lane];
  for (int j = beg + 1; j <= end; ++j) {
    int2 e1 = e0;
    ushort4 bv = b0;
    if (j < end) {
      e1 = eto[j];
      b0 = ((const ushort4*)(Bm + (size_t)e1.x * 256))[lane];
    }
    float h0 = fmaxf(a0 + bf2f(bv.x), 0.f);
    float h1 = fmaxf(a1 + bf2f(bv.y), 0.f);
    float h2 = fmaxf(a2 + bf2f(bv.z), 0.f);
    float h3 = fmaxf(a3 + bf2f(bv.w), 0.f);
    float p = h0 * w.x + h1 * w.y + h2 * w.z + h3 * w.w;
#pragma unroll
    for (int off = 32; off > 0; off >>= 1) p += __shfl_down(p, off, 64);
    if (lane == 0) out[e0.y] = p + base;
    e0 = e1;
  }
}

extern "C" void kernel_launch(void* const* d_in, const int* in_sizes, int n_in,
                              void* d_out, int out_size, void* d_ws, size_t ws_size,
                              hipStream_t stream) {
  const float* x      = (const float*)d_in[0];
  const int*   ei     = (const int*)d_in[1];
  const float* attr   = (const float*)d_in[2];
  const int*   ewi    = (const int*)d_in[3];
  const float* p_pool = (const float*)d_in[4];
  const float* W_ih   = (const float*)d_in[5];
  const float* W_hh   = (const float*)d_in[6];
  const float* b_ih   = (const float*)d_in[7];
  const float* b_hh   = (const float*)d_in[8];
  const float* W_init = (const float*)d_in[9];
  const float* lin1_w = (const float*)d_in[10];
  const float* lin1_b = (const float*)d_in[11];
  const float* lin2_w = (const float*)d_in[12];
  const float* lin2_b = (const float*)d_in[13];
  float* out = (float*)d_out;

  const int C = 256;
  const int N = in_sizes[0] / C;   // 50000
  const int E = in_sizes[2];       // 800000

  // ---- workspace layout (256B aligned) ----
  char* ws = (char*)d_ws;
  size_t off = 0;
  auto alloc = [&](size_t bytes) {
    size_t o = off;
    off = (off + bytes + 255) & ~(size_t)255;
    return o;
  };
  float*          score  = (float*)(ws + alloc((size_t)N * 4));
  float*          pnorm  = (float*)(ws + alloc(4));
  unsigned*       sel    = (unsigned*)(ws + alloc(8));
  int*            perm   = (int*)(ws + alloc(C * 4));
  float*          tts    = (float*)(ws + alloc(C * 4));
  float*          xt     = (float*)(ws + alloc((size_t)C * C * 4));
  unsigned short* WevoT  = (unsigned short*)(ws + alloc((size_t)C * C * 2));
  unsigned short* WA     = (unsigned short*)(ws + alloc((size_t)C * C * 2));
  unsigned short* WB     = (unsigned short*)(ws + alloc((size_t)C * C * 2));
  // contiguous zero region: ghist | bcnt1 | bcnt2
  int   zeroInts = 4096 + 128 + 128;
  char* zbase    = ws + alloc((size_t)zeroInts * 4);
  int* ghist = (int*)zbase;
  int* bcnt1 = (int*)(zbase + 4096 * 4);
  int* bcnt2 = (int*)(zbase + 4096 * 4 + 128 * 4);
  int*            bbase1 = (int*)(ws + alloc((NBUCK + 1) * 4));
  int*            bbase2 = (int*)(ws + alloc((NBUCK + 1) * 4));
  int*            gcur1  = (int*)(ws + alloc(128 * 4));
  int*            gcur2  = (int*)(ws + alloc(128 * 4));
  float*          dinv   = (float*)(ws + alloc((size_t)N * 4));
  int*            rowp1  = (int*)(ws + alloc((size_t)(N + 1) * 4));
  int*            rowp2  = (int*)(ws + alloc((size_t)(N + 1) * 4));
  int2*           stage1 = (int2*)(ws + alloc((size_t)E * 8));
  int2*           stage2 = (int2*)(ws + alloc((size_t)E * 8));
  int2*           esv    = (int2*)(ws + alloc((size_t)E * 8));
  int2*           eto    = (int2*)(ws + alloc((size_t)E * 8));
  unsigned short* xh     = (unsigned short*)(ws + alloc((size_t)N * C * 2));
  unsigned short* xwh    = (unsigned short*)(ws + alloc((size_t)N * C * 2));
  unsigned short* Bbf    = (unsigned short*)(ws + alloc((size_t)N * C * 2));
  // aliases (stream-ordered producers/consumers):
  unsigned short* ne  = xh;   // xh dead after GEMM1
  unsigned short* Abf = xwh;  // xwh dead after gather

  // 0) zero ghist/bcnt in one tiny launch
  zero_kernel<<<(zeroInts / 4 + 255) / 256, 256, 0, stream>>>((float4*)zbase, zeroInts / 4);

  // 1) score + bf16 cast of x (single pass over x)
  pnorm_kernel<<<1, 64, 0, stream>>>(p_pool, pnorm);
  score_cast_kernel<<<(N + 3) / 4, 256, 0, stream>>>(x, p_pool, pnorm, score, xh, N);

  // 2) exact top-256 (12-bit histogram -> bin-floor threshold -> collect+sort)
  hist12_kernel<<<64, 256, 0, stream>>>(score, N, ghist);
  select12_kernel<<<1, 1024, 0, stream>>>(ghist, C, sel);
  topk_collect_sort<<<1, 1024, 0, stream>>>(score, N, C, sel, perm, tts);

  // 3) x_tilde
  xtilde_kernel<<<C, C, 0, stream>>>(x, perm, tts, xt);

  // 4) GRU -> evolved W (transposed bf16)
  gru_kernel<<<C, C, 0, stream>>>(xt, W_init, W_ih, W_hh, b_ih, b_hh, WevoT);

  // 5) xw = x @ Wevo (bf16 MFMA, bf16 out)
  mfma_gemm_bf16<<<(N + 63) / 64, 256, 0, stream>>>(xh, WevoT, xwh, N);

  // 6) two-phase bucket sort for both CSRs (also produces deg/dinv in p2)
  bucket_hist_kernel<<<256, 256, 0, stream>>>(ei, ewi, bcnt1, bcnt2, E);
  bucket_scan_kernel<<<1, 128, 0, stream>>>(bcnt1, bcnt2, bbase1, bbase2, gcur1, gcur2,
                                            rowp1, rowp2, N, E);
  p1_conv_kernel<<<(E + 4095) / 4096, 256, 0, stream>>>(ei, attr, gcur1, stage1, E);
  p1_dec_kernel<<<(E + 4095) / 4096, 256, 0, stream>>>(ewi, gcur2, stage2, E);
  p2_conv_kernel<<<NBUCK, 256, 0, stream>>>(stage1, bbase1, esv, rowp1, dinv, N);
  p2_dec_kernel<<<NBUCK, 256, 0, stream>>>(stage2, bbase2, eto, rowp2, N);

  // 7) gather (uses dinv from p2_conv)
  gcn_gather<<<(N + 3) / 4, 256, 0, stream>>>(xwh, rowp1, esv, dinv, ne, N);

  // 8) decoder projections fused (lin1_w rows ARE the B^T layout)
  lin1_cast_kernel<<<(2 * C * C) / 256, 256, 0, stream>>>(lin1_w, WA, WB);
  mfma_gemm_bf16_dual<<<(N + 63) / 64, 256, 0, stream>>>(ne, WA, WB, Abf, Bbf, N);

  // 9) edge decode grouped by src (A-row register-resident)
  edge_decode_csr<<<(N + 3) / 4, 256, 0, stream>>>(Abf, Bbf, rowp2, eto,
                                                   lin1_b, lin2_w, lin2_b, out, N);
}

// Round 8
// 522.108 us; speedup vs baseline: 2.1861x; 1.1660x over previous
//
#include <hip/hip_runtime.h>
#include <hip/hip_bf16.h>
#include <math.h>

// ---------------------------------------------------------------------------
// EvolveGCNH + GCNConv + EdgeDecoder.
// R1: atomic scatter -> dst-CSR register gather (3574 -> 1223 us).
// R3/R4: bf16 MFMA GEMMs, bf16 operands, src-CSR grouped decode.
// R5: parallel top-k, merged CSR builds, dual GEMM (962 us).
// R7: two-phase bucket sort for both CSRs (609 us). Decode/gather now
//     latency-bound: 1 edge (512B row) per load-wait round + 6-step reduce.
// R8: (a) quad decomposition for gather/decode: 16 lanes/edge x 4 edges/wave
//         -> 4 rows (2KB) per load instruction, 4-step reduce (decode),
//         16 fp32 acc/lane + one-time cross-quad combine (gather);
//     (b) kernel fusion: pnorm->score_cast, select12->topk, xtilde->gru.
// ---------------------------------------------------------------------------

typedef __attribute__((ext_vector_type(8))) short bf16x8;
typedef __attribute__((ext_vector_type(8))) unsigned short u16x8;
typedef __attribute__((ext_vector_type(4))) float f32x4;

#define WSHIFT 9              // 512 nodes per bucket
#define WMASK 511
#define NBUCK 98              // ceil(50000/512)

__device__ __forceinline__ unsigned f2key(float f) {
  unsigned u = __float_as_uint(f);
  return (u & 0x80000000u) ? ~u : (u | 0x80000000u);
}

// round-to-nearest-even fp32 -> bf16 bits
__device__ __forceinline__ unsigned short f2bf(float f) {
  unsigned u = __float_as_uint(f);
  unsigned r = u + 0x7fffu + ((u >> 16) & 1u);
  return (unsigned short)(r >> 16);
}
__device__ __forceinline__ float bf2f(unsigned short h) {
  return __uint_as_float((unsigned)h << 16);
}

__global__ void zero_kernel(float4* __restrict__ p, int n4) {
  int i = blockIdx.x * blockDim.x + threadIdx.x;
  if (i < n4) p[i] = make_float4(0.f, 0.f, 0.f, 0.f);
}

// score (incl. ||p|| computed per-block) + bf16 cast of x in one pass
__global__ __launch_bounds__(256) void score_cast_kernel(const float* __restrict__ x,
                                                         const float* __restrict__ p,
                                                         float* __restrict__ score,
                                                         unsigned short* __restrict__ xh, int N) {
  int node = blockIdx.x * 4 + (threadIdx.x >> 6);
  int lane = threadIdx.x & 63;
  if (node >= N) return;
  float4 xv = ((const float4*)(x + (size_t)node * 256))[lane];
  ushort4 hv;
  hv.x = f2bf(xv.x);
  hv.y = f2bf(xv.y);
  hv.z = f2bf(xv.z);
  hv.w = f2bf(xv.w);
  ((ushort4*)(xh + (size_t)node * 256))[lane] = hv;
  float4 pv = ((const float4*)p)[lane];
  float s = xv.x * pv.x + xv.y * pv.y + xv.z * pv.z + xv.w * pv.w;
  float sp = pv.x * pv.x + pv.y * pv.y + pv.z * pv.z + pv.w * pv.w;
#pragma unroll
  for (int off = 32; off > 0; off >>= 1) {
    s += __shfl_down(s, off, 64);
    sp += __shfl_down(sp, off, 64);
  }
  if (lane == 0) score[node] = s / sqrtf(sp);
}

// grid-wide histogram of the top 12 key bits (4096 bins)
__global__ __launch_bounds__(256) void hist12_kernel(const float* __restrict__ score, int n,
                                                     int* __restrict__ gh) {
  __shared__ int lh[4096];
  int tid = threadIdx.x;
  for (int i = tid; i < 4096; i += 256) lh[i] = 0;
  __syncthreads();
  int idx = blockIdx.x * 256 + tid;
  int stride = gridDim.x * 256;
  for (int i = idx; i < n; i += stride) {
    unsigned key = f2key(score[i]);
    atomicAdd(&lh[key >> 20], 1);
  }
  __syncthreads();
  for (int i = tid; i < 4096; i += 256) {
    int v = lh[i];
    if (v) atomicAdd(&gh[i], v);
  }
}

// select (suffix-scan over 4096-bin histogram -> bin-floor threshold) fused
// with collect + bitonic sort (key desc, idx asc) -> perm[k], tanh(score).
__global__ __launch_bounds__(1024) void topk_kernel(const float* __restrict__ score, int n, int k,
                                                    const int* __restrict__ gh,
                                                    int* __restrict__ perm,
                                                    float* __restrict__ tts) {
  __shared__ int part[1024];
  __shared__ unsigned sT;
  int tid = threadIdx.x;
  {
    int b0 = tid * 4;
    int s0 = gh[b0], s1 = gh[b0 + 1], s2 = gh[b0 + 2], s3 = gh[b0 + 3];
    part[tid] = s0 + s1 + s2 + s3;
    __syncthreads();
    for (int off = 1; off < 1024; off <<= 1) {
      int v = part[tid];
      int add = (tid + off < 1024) ? part[tid + off] : 0;
      __syncthreads();
      part[tid] = v + add;
      __syncthreads();
    }
    int sufChunk = part[tid];
    int sufNext = (tid < 1023) ? part[tid + 1] : 0;
    if (sufNext < k && sufChunk >= k) {
      int run = sufNext;
      int b;
      run += s3;
      if (run >= k) b = b0 + 3;
      else {
        run += s2;
        if (run >= k) b = b0 + 2;
        else {
          run += s1;
          b = (run >= k) ? b0 + 1 : b0;
        }
      }
      sT = ((unsigned)b) << 20;
    }
  }
  __syncthreads();
  unsigned T = sT;
  __shared__ unsigned keys[1024];
  __shared__ int idxs[1024];
  __shared__ int cnt;
  if (tid == 0) cnt = 0;
  keys[tid] = 0u;
  idxs[tid] = 0x7fffffff;
  __syncthreads();
  for (int i = tid; i < n; i += 1024) {
    unsigned key = f2key(score[i]);
    if (key >= T) {
      int p = atomicAdd(&cnt, 1);
      if (p < 1024) { keys[p] = key; idxs[p] = i; }
    }
  }
  __syncthreads();
  for (int size = 2; size <= 1024; size <<= 1) {
    for (int stride = size >> 1; stride > 0; stride >>= 1) {
      int j = tid ^ stride;
      if (j > tid) {
        unsigned ka = keys[tid], kb = keys[j];
        int ia = idxs[tid], ib = idxs[j];
        bool aBefore = (ka > kb) || (ka == kb && ia < ib);
        bool up = ((tid & size) == 0);
        if (aBefore != up) {
          keys[tid] = kb; keys[j] = ka;
          idxs[tid] = ib; idxs[j] = ia;
        }
      }
      __syncthreads();
    }
  }
  if (tid < k) {
    int idx = idxs[tid];
    perm[tid] = idx;
    tts[tid] = tanhf(score[idx]);
  }
}

// GRU step with x_tilde computed inline (row i = x[perm[i]] * tts[i]);
// writes evolved W TRANSPOSED as bf16: WevoT[n*256 + k] = bf16(W[k][n])
__global__ __launch_bounds__(256) void gru_kernel(const float* __restrict__ x,
                                                  const int* __restrict__ perm,
                                                  const float* __restrict__ tts,
                                                  const float* __restrict__ Wi,
                                                  const float* __restrict__ W_ih,
                                                  const float* __restrict__ W_hh,
                                                  const float* __restrict__ b_ih,
                                                  const float* __restrict__ b_hh,
                                                  unsigned short* __restrict__ WevoT) {
  int i = blockIdx.x, j = threadIdx.x;  // i = k-row of W, j = n-col
  __shared__ float sx[256], sh[256];
  sx[j] = x[(size_t)perm[i] * 256 + j] * tts[i];
  sh[j] = Wi[i * 256 + j];
  __syncthreads();
  float gi[3], gh[3];
#pragma unroll
  for (int g = 0; g < 3; ++g) {
    int row = g * 256 + j;
    const float4* wi4 = (const float4*)(W_ih + (size_t)row * 256);
    const float4* wh4 = (const float4*)(W_hh + (size_t)row * 256);
    float si = 0.f, s2 = 0.f;
    for (int k4 = 0; k4 < 64; ++k4) {
      float4 wv = wi4[k4];
      float4 hv = wh4[k4];
      int k = k4 * 4;
      si += sx[k] * wv.x + sx[k + 1] * wv.y + sx[k + 2] * wv.z + sx[k + 3] * wv.w;
      s2 += sh[k] * hv.x + sh[k + 1] * hv.y + sh[k + 2] * hv.z + sh[k + 3] * hv.w;
    }
    gi[g] = si + b_ih[row];
    gh[g] = s2 + b_hh[row];
  }
  float r = 1.f / (1.f + expf(-(gi[0] + gh[0])));
  float z = 1.f / (1.f + expf(-(gi[1] + gh[1])));
  float nn = tanhf(gi[2] + r * gh[2]);
  float w = (1.f - z) * nn + z * sh[j];
  WevoT[(size_t)j * 256 + i] = f2bf(w);
}

// lin1_w [256][512] -> WA/WB bf16 each [256][256] at [n][k] (= B^T layout)
__global__ __launch_bounds__(256) void lin1_cast_kernel(const float* __restrict__ lin1,
                                                        unsigned short* __restrict__ WA,
                                                        unsigned short* __restrict__ WB) {
  int idx = blockIdx.x * 256 + threadIdx.x;  // 131072 total
  int n = idx >> 9, k = idx & 511;
  unsigned short h = f2bf(lin1[idx]);
  if (k < 256)
    WA[n * 256 + k] = h;
  else
    WB[n * 256 + (k - 256)] = h;
}

// ---------------------------------------------------------------------------
// Pure-bf16 MFMA GEMM: C[M,256] = A[M,256] @ B[256,256], bf16 in/out, fp32 acc.
// A row-major bf16; B as B^T rows (BT[n][k]). Layouts HW-verified (R3/R4).
// ---------------------------------------------------------------------------
__global__ __launch_bounds__(256) void mfma_gemm_bf16(const unsigned short* __restrict__ A,
                                                      const unsigned short* __restrict__ BT,
                                                      unsigned short* __restrict__ Cout, int M) {
  int tid = threadIdx.x;
  int wave = tid >> 6, lane = tid & 63;
  int quad = lane >> 4, r16 = lane & 15;
  int n0 = wave * 64;
  int mbase = blockIdx.x * 64;

  f32x4 acc[4][4];
#pragma unroll
  for (int i = 0; i < 4; ++i)
#pragma unroll
    for (int j = 0; j < 4; ++j) acc[i][j] = (f32x4){0.f, 0.f, 0.f, 0.f};

  for (int k0 = 0; k0 < 256; k0 += 32) {
    int koff = k0 + quad * 8;
    bf16x8 af[4], bf[4];
#pragma unroll
    for (int mt = 0; mt < 4; ++mt) {
      int row = mbase + mt * 16 + r16;
      row = row < M ? row : M - 1;
      af[mt] = *(const bf16x8*)(A + (size_t)row * 256 + koff);
    }
#pragma unroll
    for (int nt = 0; nt < 4; ++nt) {
      int nrow = n0 + nt * 16 + r16;
      bf[nt] = *(const bf16x8*)(BT + (size_t)nrow * 256 + koff);
    }
#pragma unroll
    for (int mt = 0; mt < 4; ++mt)
#pragma unroll
      for (int nt = 0; nt < 4; ++nt)
        acc[mt][nt] = __builtin_amdgcn_mfma_f32_16x16x32_bf16(af[mt], bf[nt], acc[mt][nt], 0, 0, 0);
  }
#pragma unroll
  for (int mt = 0; mt < 4; ++mt) {
#pragma unroll
    for (int rr = 0; rr < 4; ++rr) {
      int grow = mbase + mt * 16 + quad * 4 + rr;
      if (grow < M) {
#pragma unroll
        for (int nt = 0; nt < 4; ++nt)
          Cout[(size_t)grow * 256 + n0 + nt * 16 + r16] = f2bf(acc[mt][nt][rr]);
      }
    }
  }
}

// Dual variant: reads A once, produces C1 = A@B1 and C2 = A@B2.
__global__ __launch_bounds__(256) void mfma_gemm_bf16_dual(const unsigned short* __restrict__ A,
                                                           const unsigned short* __restrict__ BT1,
                                                           const unsigned short* __restrict__ BT2,
                                                           unsigned short* __restrict__ C1,
                                                           unsigned short* __restrict__ C2, int M) {
  int tid = threadIdx.x;
  int wave = tid >> 6, lane = tid & 63;
  int quad = lane >> 4, r16 = lane & 15;
  int n0 = wave * 64;
  int mbase = blockIdx.x * 64;

  f32x4 acc1[4][4], acc2[4][4];
#pragma unroll
  for (int i = 0; i < 4; ++i)
#pragma unroll
    for (int j = 0; j < 4; ++j) {
      acc1[i][j] = (f32x4){0.f, 0.f, 0.f, 0.f};
      acc2[i][j] = (f32x4){0.f, 0.f, 0.f, 0.f};
    }

  for (int k0 = 0; k0 < 256; k0 += 32) {
    int koff = k0 + quad * 8;
    bf16x8 af[4], b1[4], b2[4];
#pragma unroll
    for (int mt = 0; mt < 4; ++mt) {
      int row = mbase + mt * 16 + r16;
      row = row < M ? row : M - 1;
      af[mt] = *(const bf16x8*)(A + (size_t)row * 256 + koff);
    }
#pragma unroll
    for (int nt = 0; nt < 4; ++nt) {
      int nrow = n0 + nt * 16 + r16;
      b1[nt] = *(const bf16x8*)(BT1 + (size_t)nrow * 256 + koff);
      b2[nt] = *(const bf16x8*)(BT2 + (size_t)nrow * 256 + koff);
    }
#pragma unroll
    for (int mt = 0; mt < 4; ++mt)
#pragma unroll
      for (int nt = 0; nt < 4; ++nt) {
        acc1[mt][nt] = __builtin_amdgcn_mfma_f32_16x16x32_bf16(af[mt], b1[nt], acc1[mt][nt], 0, 0, 0);
        acc2[mt][nt] = __builtin_amdgcn_mfma_f32_16x16x32_bf16(af[mt], b2[nt], acc2[mt][nt], 0, 0, 0);
      }
  }
#pragma unroll
  for (int mt = 0; mt < 4; ++mt) {
#pragma unroll
    for (int rr = 0; rr < 4; ++rr) {
      int grow = mbase + mt * 16 + quad * 4 + rr;
      if (grow < M) {
#pragma unroll
        for (int nt = 0; nt < 4; ++nt) {
          size_t o = (size_t)grow * 256 + n0 + nt * 16 + r16;
          C1[o] = f2bf(acc1[mt][nt][rr]);
          C2[o] = f2bf(acc2[mt][nt][rr]);
        }
      }
    }
  }
}

// ---- two-phase bucket sort for both CSRs -----------------------------------

// phase 0: bucket histogram for conv-dst and decoder-src (LDS-aggregated)
__global__ __launch_bounds__(256) void bucket_hist_kernel(const int* __restrict__ ei,
                                                          const int* __restrict__ ewi,
                                                          int* __restrict__ bcnt1,
                                                          int* __restrict__ bcnt2, int E) {
  __shared__ int c1[128], c2[128];
  int tid = threadIdx.x;
  if (tid < 128) { c1[tid] = 0; c2[tid] = 0; }
  __syncthreads();
  int idx = blockIdx.x * 256 + tid;
  int stride = gridDim.x * 256;
  for (int e = idx; e < E; e += stride) {
    atomicAdd(&c1[ei[E + e] >> WSHIFT], 1);
    atomicAdd(&c2[ewi[e] >> WSHIFT], 1);
  }
  __syncthreads();
  if (tid < 128) {
    if (c1[tid]) atomicAdd(&bcnt1[tid], c1[tid]);
    if (c2[tid]) atomicAdd(&bcnt2[tid], c2[tid]);
  }
}

// phase 0b: scan bucket counts -> bases + cursors; also rowp[N] = E
__global__ __launch_bounds__(128) void bucket_scan_kernel(const int* __restrict__ bcnt1,
                                                          const int* __restrict__ bcnt2,
                                                          int* __restrict__ bbase1,
                                                          int* __restrict__ bbase2,
                                                          int* __restrict__ gcur1,
                                                          int* __restrict__ gcur2,
                                                          int* __restrict__ rowp1,
                                                          int* __restrict__ rowp2, int N, int E) {
  __shared__ int ss[128];
  int tid = threadIdx.x;
  // CSR 1
  int v = (tid < NBUCK) ? bcnt1[tid] : 0;
  ss[tid] = v;
  __syncthreads();
  for (int off = 1; off < 128; off <<= 1) {
    int a = ss[tid];
    int b = (tid >= off) ? ss[tid - off] : 0;
    __syncthreads();
    ss[tid] = a + b;
    __syncthreads();
  }
  int excl = ss[tid] - v;
  if (tid < NBUCK) { bbase1[tid] = excl; gcur1[tid] = excl; }
  if (tid == NBUCK - 1) bbase1[NBUCK] = excl + v;
  __syncthreads();
  // CSR 2
  v = (tid < NBUCK) ? bcnt2[tid] : 0;
  ss[tid] = v;
  __syncthreads();
  for (int off = 1; off < 128; off <<= 1) {
    int a = ss[tid];
    int b = (tid >= off) ? ss[tid - off] : 0;
    __syncthreads();
    ss[tid] = a + b;
    __syncthreads();
  }
  excl = ss[tid] - v;
  if (tid < NBUCK) { bbase2[tid] = excl; gcur2[tid] = excl; }
  if (tid == NBUCK - 1) bbase2[NBUCK] = excl + v;
  if (tid == 0) { rowp1[N] = E; rowp2[N] = E; }
}

// phase 1 (conv): tile-ranked scatter into bucket staging.
// stage.x = src | (dstLocal<<16), stage.y = attr bits
__global__ __launch_bounds__(256) void p1_conv_kernel(const int* __restrict__ ei,
                                                      const float* __restrict__ attr,
                                                      int* __restrict__ gcur,
                                                      int2* __restrict__ stage, int E) {
  __shared__ int cnt[128], cur[128];
  int tid = threadIdx.x;
  int base = blockIdx.x * 4096;
  if (tid < 128) cnt[tid] = 0;
  __syncthreads();
  int bk[16];
  int2 pl[16];
#pragma unroll
  for (int i = 0; i < 16; ++i) {
    int e = base + i * 256 + tid;
    bk[i] = -1;
    if (e < E) {
      int d = ei[E + e];
      int s = ei[e];
      bk[i] = d >> WSHIFT;
      pl[i] = make_int2(s | ((d & WMASK) << 16), __float_as_int(attr[e]));
      atomicAdd(&cnt[bk[i]], 1);
    }
  }
  __syncthreads();
  if (tid < NBUCK) {
    int c = cnt[tid];
    cur[tid] = c ? atomicAdd(&gcur[tid], c) : 0;
  }
  __syncthreads();
#pragma unroll
  for (int i = 0; i < 16; ++i) {
    if (bk[i] >= 0) {
      int pos = atomicAdd(&cur[bk[i]], 1);
      stage[pos] = pl[i];
    }
  }
}

// phase 1 (decoder): stage.x = dst | (srcLocal<<16), stage.y = edge_id
__global__ __launch_bounds__(256) void p1_dec_kernel(const int* __restrict__ ewi,
                                                     int* __restrict__ gcur,
                                                     int2* __restrict__ stage, int E) {
  __shared__ int cnt[128], cur[128];
  int tid = threadIdx.x;
  int base = blockIdx.x * 4096;
  if (tid < 128) cnt[tid] = 0;
  __syncthreads();
  int bk[16];
  int2 pl[16];
#pragma unroll
  for (int i = 0; i < 16; ++i) {
    int e = base + i * 256 + tid;
    bk[i] = -1;
    if (e < E) {
      int s = ewi[e];
      int d = ewi[E + e];
      bk[i] = s >> WSHIFT;
      pl[i] = make_int2(d | ((s & WMASK) << 16), e);
      atomicAdd(&cnt[bk[i]], 1);
    }
  }
  __syncthreads();
  if (tid < NBUCK) {
    int c = cnt[tid];
    cur[tid] = c ? atomicAdd(&gcur[tid], c) : 0;
  }
  __syncthreads();
#pragma unroll
  for (int i = 0; i < 16; ++i) {
    if (bk[i] >= 0) {
      int pos = atomicAdd(&cur[bk[i]], 1);
      stage[pos] = pl[i];
    }
  }
}

// phase 2 (conv): one block per bucket. LDS node-histogram + deg accumulation,
// LDS scan -> rowp/dinv/final CSR (node-ordered). esv.x = src, esv.y = attr.
__global__ __launch_bounds__(256) void p2_conv_kernel(const int2* __restrict__ stage,
                                                      const int* __restrict__ bbase,
                                                      int2* __restrict__ esv,
                                                      int* __restrict__ rowp,
                                                      float* __restrict__ dinv, int N) {
  __shared__ int cnt[512];
  __shared__ float degs[512];
  __shared__ int pref[512];
  __shared__ int ss[256];
  int tid = threadIdx.x;
  int b = blockIdx.x;
  int beg = bbase[b], end = bbase[b + 1];
  int node0 = b << WSHIFT;
  cnt[tid] = 0; cnt[tid + 256] = 0;
  degs[tid] = 0.f; degs[tid + 256] = 0.f;
  __syncthreads();
  for (int j = beg + tid; j < end; j += 256) {
    int2 p = stage[j];
    int loc = p.x >> 16;
    atomicAdd(&cnt[loc], 1);
    atomicAdd(&degs[loc], __int_as_float(p.y));
  }
  __syncthreads();
  int c0 = cnt[2 * tid], c1 = cnt[2 * tid + 1];
  ss[tid] = c0 + c1;
  __syncthreads();
  for (int off = 1; off < 256; off <<= 1) {
    int a = ss[tid];
    int bb = (tid >= off) ? ss[tid - off] : 0;
    __syncthreads();
    ss[tid] = a + bb;
    __syncthreads();
  }
  int excl = (tid ? ss[tid - 1] : 0);
  pref[2 * tid] = excl;
  pref[2 * tid + 1] = excl + c0;
  __syncthreads();
#pragma unroll
  for (int h = 0; h < 2; ++h) {
    int i = tid + h * 256;
    int node = node0 + i;
    if (node < N) {
      rowp[node] = beg + pref[i];
      float d = degs[i];
      dinv[node] = d > 0.f ? 1.f / sqrtf(d) : 0.f;
    }
  }
  __syncthreads();
  for (int j = beg + tid; j < end; j += 256) {
    int2 p = stage[j];
    int loc = p.x >> 16;
    int pos = beg + atomicAdd(&pref[loc], 1);
    esv[pos] = make_int2(p.x & 0xFFFF, p.y);
  }
}

// phase 2 (decoder): same minus deg. eto.x = dst, eto.y = edge_id.
__global__ __launch_bounds__(256) void p2_dec_kernel(const int2* __restrict__ stage,
                                                     const int* __restrict__ bbase,
                                                     int2* __restrict__ eto,
                                                     int* __restrict__ rowp, int N) {
  __shared__ int cnt[512];
  __shared__ int pref[512];
  __shared__ int ss[256];
  int tid = threadIdx.x;
  int b = blockIdx.x;
  int beg = bbase[b], end = bbase[b + 1];
  int node0 = b << WSHIFT;
  cnt[tid] = 0; cnt[tid + 256] = 0;
  __syncthreads();
  for (int j = beg + tid; j < end; j += 256) {
    int2 p = stage[j];
    atomicAdd(&cnt[p.x >> 16], 1);
  }
  __syncthreads();
  int c0 = cnt[2 * tid], c1 = cnt[2 * tid + 1];
  ss[tid] = c0 + c1;
  __syncthreads();
  for (int off = 1; off < 256; off <<= 1) {
    int a = ss[tid];
    int bb = (tid >= off) ? ss[tid - off] : 0;
    __syncthreads();
    ss[tid] = a + bb;
    __syncthreads();
  }
  int excl = (tid ? ss[tid - 1] : 0);
  pref[2 * tid] = excl;
  pref[2 * tid + 1] = excl + c0;
  __syncthreads();
#pragma unroll
  for (int h = 0; h < 2; ++h) {
    int i = tid + h * 256;
    int node = node0 + i;
    if (node < N) rowp[node] = beg + pref[i];
  }
  __syncthreads();
  for (int j = beg + tid; j < end; j += 256) {
    int2 p = stage[j];
    int loc = p.x >> 16;
    int pos = beg + atomicAdd(&pref[loc], 1);
    eto[pos] = make_int2(p.x & 0xFFFF, p.y);
  }
}

// one wave per dst node, quad decomposition: 16 lanes/edge x 4 edges/iteration.
// Lane g=lane&15 owns channels [g*16, g*16+16); quad q processes edge jb+q.
__global__ __launch_bounds__(256) void gcn_gather(const unsigned short* __restrict__ xw,
                                                  const int* __restrict__ row_ptr,
                                                  const int2* __restrict__ esv,
                                                  const float* __restrict__ dinv,
                                                  unsigned short* __restrict__ ne, int N) {
  int node = blockIdx.x * 4 + (threadIdx.x >> 6);
  int lane = threadIdx.x & 63;
  int g = lane & 15, q = lane >> 4;
  if (node >= N) return;
  int beg = row_ptr[node], end = row_ptr[node + 1];
  float acc[16];
#pragma unroll
  for (int c = 0; c < 16; ++c) acc[c] = 0.f;
  const unsigned short* xb = xw + g * 16;
  if (beg < end) {
    int e0 = beg + q;
    int2 m0 = (e0 < end) ? esv[e0] : make_int2(0, 0);
    float v0 = (e0 < end) ? dinv[m0.x] * __int_as_float(m0.y) : 0.f;
    u16x8 r0a = *(const u16x8*)(xb + (size_t)m0.x * 256);
    u16x8 r0b = *(const u16x8*)(xb + (size_t)m0.x * 256 + 8);
    for (int jb = beg; jb < end; jb += 4) {
      int2 m1 = make_int2(0, 0);
      float v1 = 0.f;
      u16x8 r1a = r0a, r1b = r0b;
      if (jb + 4 < end) {
        int e1 = jb + 4 + q;
        m1 = (e1 < end) ? esv[e1] : make_int2(0, 0);
        v1 = (e1 < end) ? dinv[m1.x] * __int_as_float(m1.y) : 0.f;
        r1a = *(const u16x8*)(xb + (size_t)m1.x * 256);
        r1b = *(const u16x8*)(xb + (size_t)m1.x * 256 + 8);
      }
#pragma unroll
      for (int c = 0; c < 8; ++c) acc[c] += bf2f(r0a[c]) * v0;
#pragma unroll
      for (int c = 0; c < 8; ++c) acc[8 + c] += bf2f(r0b[c]) * v0;
      v0 = v1; r0a = r1a; r0b = r1b;
      m0 = m1;
    }
  }
  // cross-quad combine (each quad holds a partial over the same channels)
#pragma unroll
  for (int c = 0; c < 16; ++c) {
    acc[c] += __shfl_xor(acc[c], 16, 64);
    acc[c] += __shfl_xor(acc[c], 32, 64);
  }
  if (q == 0) {
    float dd = dinv[node];
    u16x8 o0, o1;
#pragma unroll
    for (int c = 0; c < 8; ++c) {
      o0[c] = f2bf(acc[c] * dd);
      o1[c] = f2bf(acc[8 + c] * dd);
    }
    *(u16x8*)(ne + (size_t)node * 256 + g * 16) = o0;
    *(u16x8*)(ne + (size_t)node * 256 + g * 16 + 8) = o1;
  }
}

// decode grouped by src, quad decomposition: 16 lanes/edge x 4 edges/iteration.
// A[s]+b1 and w2 register-resident per lane (16 channels); 4-step quad reduce.
__global__ __launch_bounds__(256) void edge_decode_csr(const unsigned short* __restrict__ A,
                                                       const unsigned short* __restrict__ Bm,
                                                       const int* __restrict__ row_ptr,
                                                       const int2* __restrict__ eto,
                                                       const float* __restrict__ b1,
                                                       const float* __restrict__ w2,
                                                       const float* __restrict__ b2,
                                                       float* __restrict__ out, int N) {
  int node = blockIdx.x * 4 + (threadIdx.x >> 6);
  int lane = threadIdx.x & 63;
  int g = lane & 15, q = lane >> 4;
  if (node >= N) return;
  int beg = row_ptr[node], end = row_ptr[node + 1];
  if (beg >= end) return;
  float a[16], w[16];
  {
    u16x8 a0 = *(const u16x8*)(A + (size_t)node * 256 + g * 16);
    u16x8 a1 = *(const u16x8*)(A + (size_t)node * 256 + g * 16 + 8);
    const float4* bp = (const float4*)(b1 + g * 16);
    const float4* wp = (const float4*)(w2 + g * 16);
#pragma unroll
    for (int i = 0; i < 4; ++i) {
      float4 bv = bp[i];
      float4 wv = wp[i];
      a[i * 4 + 0] = (i < 2 ? bf2f(a0[i * 4 + 0]) : bf2f(a1[i * 4 - 8])) + bv.x;
      a[i * 4 + 1] = (i < 2 ? bf2f(a0[i * 4 + 1]) : bf2f(a1[i * 4 - 7])) + bv.y;
      a[i * 4 + 2] = (i < 2 ? bf2f(a0[i * 4 + 2]) : bf2f(a1[i * 4 - 6])) + bv.z;
      a[i * 4 + 3] = (i < 2 ? bf2f(a0[i * 4 + 3]) : bf2f(a1[i * 4 - 5])) + bv.w;
      w[i * 4 + 0] = wv.x;
      w[i * 4 + 1] = wv.y;
      w[i * 4 + 2] = wv.z;
      w[i * 4 + 3] = wv.w;
    }
  }
  float base = b2[0];
  const unsigned short* Bb = Bm + g * 16;
  int e0 = beg + q;
  int2 m0 = (e0 < end) ? eto[e0] : make_int2(0, -1);
  u16x8 r0a = *(const u16x8*)(Bb + (size_t)m0.x * 256);
  u16x8 r0b = *(const u16x8*)(Bb + (size_t)m0.x * 256 + 8);
  for (int jb = beg; jb < end; jb += 4) {
    int2 m1 = make_int2(0, -1);
    u16x8 r1a = r0a, r1b = r0b;
    if (jb + 4 < end) {
      int e1 = jb + 4 + q;
      m1 = (e1 < end) ? eto[e1] : make_int2(0, -1);
      r1a = *(const u16x8*)(Bb + (size_t)m1.x * 256);
      r1b = *(const u16x8*)(Bb + (size_t)m1.x * 256 + 8);
    }
    float s = 0.f;
#pragma unroll
    for (int c = 0; c < 8; ++c) s += fmaxf(a[c] + bf2f(r0a[c]), 0.f) * w[c];
#pragma unroll
    for (int c = 0; c < 8; ++c) s += fmaxf(a[8 + c] + bf2f(r0b[c]), 0.f) * w[8 + c];
    s += __shfl_xor(s, 1, 64);
    s += __shfl_xor(s, 2, 64);
    s += __shfl_xor(s, 4, 64);
    s += __shfl_xor(s, 8, 64);
    if (g == 0 && m0.y >= 0) out[m0.y] = s + base;
    m0 = m1; r0a = r1a; r0b = r1b;
  }
}

extern "C" void kernel_launch(void* const* d_in, const int* in_sizes, int n_in,
                              void* d_out, int out_size, void* d_ws, size_t ws_size,
                              hipStream_t stream) {
  const float* x      = (const float*)d_in[0];
  const int*   ei     = (const int*)d_in[1];
  const float* attr   = (const float*)d_in[2];
  const int*   ewi    = (const int*)d_in[3];
  const float* p_pool = (const float*)d_in[4];
  const float* W_ih   = (const float*)d_in[5];
  const float* W_hh   = (const float*)d_in[6];
  const float* b_ih   = (const float*)d_in[7];
  const float* b_hh   = (const float*)d_in[8];
  const float* W_init = (const float*)d_in[9];
  const float* lin1_w = (const float*)d_in[10];
  const float* lin1_b = (const float*)d_in[11];
  const float* lin2_w = (const float*)d_in[12];
  const float* lin2_b = (const float*)d_in[13];
  float* out = (float*)d_out;

  const int C = 256;
  const int N = in_sizes[0] / C;   // 50000
  const int E = in_sizes[2];       // 800000

  // ---- workspace layout (256B aligned) ----
  char* ws = (char*)d_ws;
  size_t off = 0;
  auto alloc = [&](size_t bytes) {
    size_t o = off;
    off = (off + bytes + 255) & ~(size_t)255;
    return o;
  };
  float*          score  = (float*)(ws + alloc((size_t)N * 4));
  int*            perm   = (int*)(ws + alloc(C * 4));
  float*          tts    = (float*)(ws + alloc(C * 4));
  unsigned short* WevoT  = (unsigned short*)(ws + alloc((size_t)C * C * 2));
  unsigned short* WA     = (unsigned short*)(ws + alloc((size_t)C * C * 2));
  unsigned short* WB     = (unsigned short*)(ws + alloc((size_t)C * C * 2));
  // contiguous zero region: ghist | bcnt1 | bcnt2
  int   zeroInts = 4096 + 128 + 128;
  char* zbase    = ws + alloc((size_t)zeroInts * 4);
  int* ghist = (int*)zbase;
  int* bcnt1 = (int*)(zbase + 4096 * 4);
  int* bcnt2 = (int*)(zbase + 4096 * 4 + 128 * 4);
  int*            bbase1 = (int*)(ws + alloc((NBUCK + 1) * 4));
  int*            bbase2 = (int*)(ws + alloc((NBUCK + 1) * 4));
  int*            gcur1  = (int*)(ws + alloc(128 * 4));
  int*            gcur2  = (int*)(ws + alloc(128 * 4));
  float*          dinv   = (float*)(ws + alloc((size_t)N * 4));
  int*            rowp1  = (int*)(ws + alloc((size_t)(N + 1) * 4));
  int*            rowp2  = (int*)(ws + alloc((size_t)(N + 1) * 4));
  int2*           stage1 = (int2*)(ws + alloc((size_t)E * 8));
  int2*           stage2 = (int2*)(ws + alloc((size_t)E * 8));
  int2*           esv    = (int2*)(ws + alloc((size_t)E * 8));
  int2*           eto    = (int2*)(ws + alloc((size_t)E * 8));
  unsigned short* xh     = (unsigned short*)(ws + alloc((size_t)N * C * 2));
  unsigned short* xwh    = (unsigned short*)(ws + alloc((size_t)N * C * 2));
  unsigned short* Bbf    = (unsigned short*)(ws + alloc((size_t)N * C * 2));
  // aliases (stream-ordered producers/consumers):
  unsigned short* ne  = xh;   // xh dead after GEMM1
  unsigned short* Abf = xwh;  // xwh dead after gather

  // 0) zero ghist/bcnt in one tiny launch
  zero_kernel<<<(zeroInts / 4 + 255) / 256, 256, 0, stream>>>((float4*)zbase, zeroInts / 4);

  // 1) score (+||p|| per block) + bf16 cast of x
  score_cast_kernel<<<(N + 3) / 4, 256, 0, stream>>>(x, p_pool, score, xh, N);

  // 2) exact top-256: 12-bit histogram -> fused select+collect+sort
  hist12_kernel<<<64, 256, 0, stream>>>(score, N, ghist);
  topk_kernel<<<1, 1024, 0, stream>>>(score, N, C, ghist, perm, tts);

  // 3+4) GRU (x_tilde inline) -> evolved W (transposed bf16)
  gru_kernel<<<C, C, 0, stream>>>(x, perm, tts, W_init, W_ih, W_hh, b_ih, b_hh, WevoT);

  // 5) xw = x @ Wevo (bf16 MFMA, bf16 out)
  mfma_gemm_bf16<<<(N + 63) / 64, 256, 0, stream>>>(xh, WevoT, xwh, N);

  // 6) two-phase bucket sort for both CSRs (also produces deg/dinv in p2)
  bucket_hist_kernel<<<256, 256, 0, stream>>>(ei, ewi, bcnt1, bcnt2, E);
  bucket_scan_kernel<<<1, 128, 0, stream>>>(bcnt1, bcnt2, bbase1, bbase2, gcur1, gcur2,
                                            rowp1, rowp2, N, E);
  p1_conv_kernel<<<(E + 4095) / 4096, 256, 0, stream>>>(ei, attr, gcur1, stage1, E);
  p1_dec_kernel<<<(E + 4095) / 4096, 256, 0, stream>>>(ewi, gcur2, stage2, E);
  p2_conv_kernel<<<NBUCK, 256, 0, stream>>>(stage1, bbase1, esv, rowp1, dinv, N);
  p2_dec_kernel<<<NBUCK, 256, 0, stream>>>(stage2, bbase2, eto, rowp2, N);

  // 7) gather (quad decomposition)
  gcn_gather<<<(N + 3) / 4, 256, 0, stream>>>(xwh, rowp1, esv, dinv, ne, N);

  // 8) decoder projections fused (lin1_w rows ARE the B^T layout)
  lin1_cast_kernel<<<(2 * C * C) / 256, 256, 0, stream>>>(lin1_w, WA, WB);
  mfma_gemm_bf16_dual<<<(N + 63) / 64, 256, 0, stream>>>(ne, WA, WB, Abf, Bbf, N);

  // 9) edge decode (quad decomposition)
  edge_decode_csr<<<(N + 3) / 4, 256, 0, stream>>>(Abf, Bbf, rowp2, eto,
                                                   lin1_b, lin2_w, lin2_b, out, N);
}